// Round 6
// baseline (1230.523 us; speedup 1.0000x reference)
//
#include <hip/hip_runtime.h>

#define DIM 1536
#define NH 12
#define HD 128
#define S_LEN 5400
#define SPAD 5504      // vt row stride (43*128)
#define MPAD 5504      // 43*128 (GEMM M tiles / flash q tiles)
#define NQKV 4608
#define EPS_NORM 1e-6f

typedef __bf16 bf16_t;
typedef __bf16 bf16x8 __attribute__((ext_vector_type(8)));
typedef __bf16 bf16x4 __attribute__((ext_vector_type(4)));
typedef __bf16 bf16x2 __attribute__((ext_vector_type(2)));
typedef float  f32x4  __attribute__((ext_vector_type(4)));
typedef float  f32x16 __attribute__((ext_vector_type(16)));
typedef int    i32x2  __attribute__((ext_vector_type(2)));

// async global->LDS, 16B per lane; LDS dest is wave-uniform base + lane*16
#define GLOAD_LDS16(gp, lp) __builtin_amdgcn_global_load_lds( \
    (__attribute__((address_space(1))) void*)(void*)(gp),     \
    (__attribute__((address_space(3))) void*)(lp), 16, 0, 0)

// pack two f32 -> bf16x2 word (compiler emits cvt_pk; don't hand-write asm, m240)
__device__ __forceinline__ unsigned int pkbf(float a, float b) {
  union { bf16x2 h; unsigned int u; } c;
  c.h[0] = (__bf16)a; c.h[1] = (__bf16)b;
  return c.u;
}

// cross-half (lane ^ 32) reduce via permlane32_swap BUILTIN (two modeled defs,
// no register-coalescing hazard; max/sum of the result pair is direction-agnostic)
__device__ __forceinline__ float xhalf_max(float x) {
  i32x2 r = __builtin_amdgcn_permlane32_swap(__float_as_int(x), __float_as_int(x),
                                             false, false);
  return fmaxf(__int_as_float(r.x), __int_as_float(r.y));
}
__device__ __forceinline__ float xhalf_sum(float x) {
  i32x2 r = __builtin_amdgcn_permlane32_swap(__float_as_int(x), __float_as_int(x),
                                             false, false);
  return __int_as_float(r.x) + __int_as_float(r.y);
}

// ---------------- conversion kernels ----------------

__global__ __launch_bounds__(256) void cvt_x_kernel(const float* __restrict__ x,
                                                    bf16_t* __restrict__ xb) {
  size_t base = ((size_t)blockIdx.x * 256 + threadIdx.x) * 4;
  if (base >= (size_t)MPAD * DIM) return;
  size_t row = base / DIM;
  float4 v = make_float4(0.f, 0.f, 0.f, 0.f);
  if (row < S_LEN) v = *(const float4*)&x[base];
  bf16x4 o; o[0] = (__bf16)v.x; o[1] = (__bf16)v.y; o[2] = (__bf16)v.z; o[3] = (__bf16)v.w;
  *(bf16x4*)&xb[base] = o;
}

__global__ __launch_bounds__(256) void cvt_wqkv_kernel(const float* __restrict__ qw,
                                                       const float* __restrict__ kw,
                                                       const float* __restrict__ vw,
                                                       bf16_t* __restrict__ wb) {
  size_t base = ((size_t)blockIdx.x * 256 + threadIdx.x) * 4;
  if (base >= (size_t)NQKV * DIM) return;
  int row = (int)(base / DIM);
  int col = (int)(base - (size_t)row * DIM);
  const float* src; int rr = row;
  if (rr >= 3072)      { src = vw; rr -= 3072; }
  else if (rr >= 1536) { src = kw; rr -= 1536; }
  else                 { src = qw; }
  float4 v = *(const float4*)&src[(size_t)rr * DIM + col];
  bf16x4 o; o[0] = (__bf16)v.x; o[1] = (__bf16)v.y; o[2] = (__bf16)v.z; o[3] = (__bf16)v.w;
  *(bf16x4*)&wb[base] = o;
}

__global__ __launch_bounds__(256) void cvt_wo_kernel(const float* __restrict__ w,
                                                     bf16_t* __restrict__ wb) {
  size_t base = ((size_t)blockIdx.x * 256 + threadIdx.x) * 4;
  if (base >= (size_t)DIM * DIM) return;
  float4 v = *(const float4*)&w[base];
  bf16x4 o; o[0] = (__bf16)v.x; o[1] = (__bf16)v.y; o[2] = (__bf16)v.z; o[3] = (__bf16)v.w;
  *(bf16x4*)&wb[base] = o;
}

// ---------------- GEMM: C[M,N] = A[M,K] @ B[N,K]^T + bias ----------------
// 2-phase pipeline: prefetch k-tile t+1 into buf^1 while computing buf.

template<bool OUT_BF16>
__global__ __launch_bounds__(256) void gemm_bt_kernel(
    const bf16_t* __restrict__ A, const bf16_t* __restrict__ B, void* __restrict__ C,
    const float* __restrict__ bias0, const float* __restrict__ bias1,
    const float* __restrict__ bias2, int M, int N, int K, int Mvalid) {
  __shared__ bf16_t As[2][128 * 32];
  __shared__ bf16_t Bs[2][128 * 32];
  int tid = threadIdx.x;
  int lane = tid & 63, wave = tid >> 6, quad = lane >> 4, l16 = lane & 15;
  int m0 = blockIdx.y * 128, n0 = blockIdx.x * 128;
  int wm = (wave >> 1) * 64, wn = (wave & 1) * 64;
  const bf16_t* Ab = A + (size_t)m0 * K;
  const bf16_t* Bb = B + (size_t)n0 * K;
  f32x4 acc[4][4] = {};

  int eo0 = tid * 8;
  int row0 = eo0 >> 5, col0 = eo0 & 31;
  int eo1 = (256 + tid) * 8;
  int row1 = eo1 >> 5, col1 = eo1 & 31;

  // prologue: stage k-tile 0 into buf 0
  GLOAD_LDS16(Ab + (size_t)row0 * K + col0, &As[0][eo0]);
  GLOAD_LDS16(Bb + (size_t)row0 * K + col0, &Bs[0][eo0]);
  GLOAD_LDS16(Ab + (size_t)row1 * K + col1, &As[0][eo1]);
  GLOAD_LDS16(Bb + (size_t)row1 * K + col1, &Bs[0][eo1]);
  asm volatile("s_waitcnt vmcnt(0)" ::: "memory");
  __builtin_amdgcn_s_barrier();
  __builtin_amdgcn_sched_barrier(0);

  int KT = K >> 5;
  for (int t = 0; t < KT; t++) {
    int cur = t & 1;
    if (t + 1 < KT) {
      int kn = (t + 1) << 5;
      GLOAD_LDS16(Ab + (size_t)row0 * K + kn + col0, &As[cur ^ 1][eo0]);
      GLOAD_LDS16(Bb + (size_t)row0 * K + kn + col0, &Bs[cur ^ 1][eo0]);
      GLOAD_LDS16(Ab + (size_t)row1 * K + kn + col1, &As[cur ^ 1][eo1]);
      GLOAD_LDS16(Bb + (size_t)row1 * K + kn + col1, &Bs[cur ^ 1][eo1]);
    }
    bf16x8 af[4], bfr[4];
#pragma unroll
    for (int i = 0; i < 4; i++)
      af[i] = *(const bf16x8*)&As[cur][(wm + i * 16 + l16) * 32 + quad * 8];
#pragma unroll
    for (int j = 0; j < 4; j++)
      bfr[j] = *(const bf16x8*)&Bs[cur][(wn + j * 16 + l16) * 32 + quad * 8];
#pragma unroll
    for (int i = 0; i < 4; i++)
#pragma unroll
      for (int j = 0; j < 4; j++)
        acc[i][j] = __builtin_amdgcn_mfma_f32_16x16x32_bf16(af[i], bfr[j], acc[i][j], 0, 0, 0);
    asm volatile("s_waitcnt vmcnt(0) lgkmcnt(0)" ::: "memory");
    __builtin_amdgcn_s_barrier();
    __builtin_amdgcn_sched_barrier(0);
  }
  // epilogue: C/D layout col=lane&15, row=quad*4+reg  [m89-verified]
#pragma unroll
  for (int j = 0; j < 4; j++) {
    int n = n0 + wn + j * 16 + l16;
    float bias = (n < 1536) ? bias0[n] : (n < 3072) ? bias1[n - 1536] : bias2[n - 3072];
#pragma unroll
    for (int i = 0; i < 4; i++) {
#pragma unroll
      for (int r = 0; r < 4; r++) {
        int m = m0 + wm + i * 16 + quad * 4 + r;
        float v = acc[i][j][r] + bias;
        if (OUT_BF16) {
          ((bf16_t*)C)[(size_t)m * N + n] = (__bf16)v;
        } else {
          if (m < Mvalid) ((float*)C)[(size_t)m * N + n] = v;
        }
      }
    }
  }
}

// ---------------- RMSNorm + RoPE for q,k ----------------
// q pre-scaled by (1/sqrt(HD)) * log2(e) so flash uses raw v_exp_f32 (2^x)
// with no per-element multiply and no logit scale.

__global__ __launch_bounds__(256) void rope_qk_kernel(
    const bf16_t* __restrict__ qkv, const float* __restrict__ nqw,
    const float* __restrict__ nkw, const float* __restrict__ fcos,
    const float* __restrict__ fsin, bf16_t* __restrict__ qout,
    bf16_t* __restrict__ kout) {
  int s = blockIdx.x;              // 0..MPAD-1
  int tid = threadIdx.x;
  bool valid = s < S_LEN;
  int f = s / 900, hh = (s / 30) % 30, ww = s % 30;
  __shared__ float red[4];
  for (int which = 0; which < 2; which++) {
    const bf16_t* src = qkv + (size_t)s * NQKV + which * DIM;
    const float* nw = which ? nkw : nqw;
    bf16_t* dst = (which ? kout : qout) + (size_t)s * DIM;
    // 0.12751742686 = (1/sqrt(128)) * log2(e)
    float osc = which ? 1.0f : 0.12751742686f;
    float v[6]; float ss = 0.f;
#pragma unroll
    for (int i = 0; i < 6; i++) {
      v[i] = valid ? (float)src[tid * 6 + i] : 0.f;
      ss += v[i] * v[i];
    }
#pragma unroll
    for (int off = 32; off >= 1; off >>= 1) ss += __shfl_down(ss, off);
    if ((tid & 63) == 0) red[tid >> 6] = ss;
    __syncthreads();
    float tot = red[0] + red[1] + red[2] + red[3];
    float rn = rsqrtf(tot * (1.f / DIM) + EPS_NORM);
    __syncthreads();   // protect red[] before next `which` iteration
#pragma unroll
    for (int i = 0; i < 3; i++) {
      int e0 = tid * 6 + 2 * i;
      int p = e0 >> 1;             // pair index; cc = p&63
      int cc = p & 63;
      int pos = (cc < 22) ? f : (cc < 43) ? hh : ww;  // split [22,21,21]
      float c = fcos[pos * 64 + cc], sn = fsin[pos * 64 + cc];
      float xr = v[2 * i] * rn * nw[e0];
      float xi = v[2 * i + 1] * rn * nw[e0 + 1];
      dst[e0]     = (__bf16)((xr * c - xi * sn) * osc);
      dst[e0 + 1] = (__bf16)((xr * sn + xi * c) * osc);
    }
  }
}

// ---------------- V transpose: qkv v-part -> vt[h][d][s] ----------------

__global__ __launch_bounds__(256) void v_transpose_kernel(const bf16_t* __restrict__ qkv,
                                                          bf16_t* __restrict__ vt) {
  __shared__ bf16_t tile[64][136];   // +8 pad
  int h = blockIdx.y, s0 = blockIdx.x * 64, tid = threadIdx.x;
#pragma unroll
  for (int it = 0; it < 4; it++) {
    int eo = (it * 256 + tid) * 8;   // 64x128 elements
    int row = eo >> 7, col = eo & 127;
    int s = s0 + row;
    bf16x8 val = {};
    if (s < S_LEN) val = *(const bf16x8*)&qkv[(size_t)s * NQKV + 3072 + h * HD + col];
    *(bf16x8*)&tile[row][col] = val;
  }
  __syncthreads();
  int d = tid & 127, j0 = (tid >> 7) * 32;
  bf16x8 outv[4];
#pragma unroll
  for (int b = 0; b < 4; b++)
#pragma unroll
    for (int j = 0; j < 8; j++) outv[b][j] = tile[j0 + b * 8 + j][d];
  size_t base = ((size_t)h * HD + d) * SPAD + s0 + j0;
#pragma unroll
  for (int b = 0; b < 4; b++) *(bf16x8*)&vt[base + b * 8] = outv[b];
}

// ---------------- flash attention (S^T = K Q^T, 32x32x16 MFMA) ----------------
// NO-LDS variant: K and V^T fragments are loaded DIRECTLY global->VGPR
// (bf16x8 = 16B per lane). Rationale (R5 accounting): pipes ran serially;
// the ds_read pipe (~6.1k cyc/CU-iter) was the largest budget, and K/V is
// L2/L1-resident (FETCH_SIZE 38MB, per-XCD set ~4.2MB with swizzle) -> LDS
// staging was pure overhead (Common-mistake #7, m169). This deletes all
// barriers/staging; waves run fully independent. LDS = epilogue scratch only.
// Per wave-iter footprint: K 64rows x 256B + V 128rows x 128B = 32KB ~ L1.
// V-frag loads issue before softmax so they land under the VALU phase.
// C/D 32x32 layout: col=lane&31, row=(reg&3)+8*(reg>>2)+4*(lane>>5)  [m74/m101]
// A/B frag: row/col=lane&31, k=(lane>>5)*8+j.

__global__ __launch_bounds__(256, 2) void flash_attn_kernel(
    const bf16_t* __restrict__ q, const bf16_t* __restrict__ k,
    const bf16_t* __restrict__ vt, bf16_t* __restrict__ o) {
  __shared__ __align__(16) bf16_t scr_all[4][32 * 64];   // 16 KB epilogue scratch
  // bijective XCD-chunked swizzle (m204): contiguous work range per XCD
  int nwg = gridDim.x;                 // 516
  int bid = blockIdx.x;
  int xcd = bid & 7, idx = bid >> 3;
  int q8 = nwg >> 3, rr = nwg & 7;
  int work = (xcd < rr ? xcd * (q8 + 1) : rr * (q8 + 1) + (xcd - rr) * q8) + idx;
  int head = work / 43;
  int s0 = (work - head * 43) * 128;

  int tid = threadIdx.x, w = tid >> 6, lane = tid & 63;
  int l31 = lane & 31, hh = lane >> 5;

  // ---- Q B-frags (loop-invariant): B[col=q][k=16kc+8hh+j]
  bf16x8 bq[8];
  {
    const bf16_t* qp = &q[(size_t)(s0 + w * 32 + l31) * DIM + head * HD + hh * 8];
#pragma unroll
    for (int kc = 0; kc < 8; kc++) bq[kc] = *(const bf16x8*)(qp + kc * 16);
  }

  // per-lane operand base pointers
  const bf16_t* kp = k + (size_t)l31 * DIM + head * HD + hh * 8;          // K row l31 (+ (kt+ns*32)*DIM), chunk kc*16
  const bf16_t* vp = vt + ((size_t)head * HD + l31) * SPAD + hh * 8;      // V^T row d=l31 (+ dt*32*SPAD), col kt+kvc*16

  float m_i = -1e30f, l_i = 0.f;
  f32x16 oacc[4] = {};   // O^T: d = dt*32 + (r&3)+8*(r>>2)+4*hh, col q = l31

  const int NT = 85;     // ceil(5400/64); reads stay < SPAD rows/cols

  for (int t = 0; t < NT; t++) {
    int kt = t * 64;

    // ---- K A-frags direct from global (L2/L1-resident)
    bf16x8 ak[16];
#pragma unroll
    for (int ns = 0; ns < 2; ns++)
#pragma unroll
      for (int kc = 0; kc < 8; kc++)
        ak[ns * 8 + kc] = *(const bf16x8*)(kp + (size_t)(kt + ns * 32) * DIM + kc * 16);

    // ---- S^T = K Q^T : 2 kv-subtiles x 8 k-chunks of 32x32x16
    f32x16 sacc[2] = {};
    __builtin_amdgcn_s_setprio(1);
#pragma unroll
    for (int ns = 0; ns < 2; ns++)
#pragma unroll
      for (int kc = 0; kc < 8; kc++)
        sacc[ns] = __builtin_amdgcn_mfma_f32_32x32x16_bf16(ak[ns * 8 + kc], bq[kc], sacc[ns], 0, 0, 0);
    __builtin_amdgcn_s_setprio(0);

    // ---- V A-frags direct from global; land under the softmax VALU phase
    bf16x8 av[16];
#pragma unroll
    for (int kvc = 0; kvc < 4; kvc++)
#pragma unroll
      for (int dt = 0; dt < 4; dt++)
        av[kvc * 4 + dt] = *(const bf16x8*)(vp + (size_t)(dt * 32) * SPAD + kt + kvc * 16);

    // ---- mask (final tile only)
    if (kt + 64 > S_LEN) {
#pragma unroll
      for (int ns = 0; ns < 2; ns++)
#pragma unroll
        for (int r = 0; r < 16; r++) {
          int kvg = kt + ns * 32 + (r & 3) + 8 * (r >> 2) + 4 * hh;
          if (kvg >= S_LEN) sacc[ns][r] = -1e30f;
        }
    }

    // ---- online softmax (log2 domain), tree max, permlane cross-half
    float mx;
    {
      float tm[8];
#pragma unroll
      for (int i = 0; i < 8; i++)
        tm[i] = fmaxf(fmaxf(sacc[0][i], sacc[0][i + 8]),
                      fmaxf(sacc[1][i], sacc[1][i + 8]));
#pragma unroll
      for (int i = 0; i < 4; i++) tm[i] = fmaxf(tm[i], tm[i + 4]);
      mx = fmaxf(fmaxf(tm[0], tm[2]), fmaxf(tm[1], tm[3]));
    }
    mx = xhalf_max(mx);
    if (!__all(mx - m_i <= 11.5f)) {   // 11.5 ~= 8*log2(e)
      float mn = fmaxf(m_i, mx);
      float al = __builtin_amdgcn_exp2f(m_i - mn);
      l_i *= al;
#pragma unroll
      for (int dt = 0; dt < 4; dt++)
#pragma unroll
        for (int r = 0; r < 16; r++) oacc[dt][r] *= al;
      m_i = mn;
    }
#pragma unroll
    for (int ns = 0; ns < 2; ns++)
#pragma unroll
      for (int r = 0; r < 16; r++)
        sacc[ns][r] = __builtin_amdgcn_exp2f(sacc[ns][r] - m_i);
    float rs;
    {
      float ts[8];
#pragma unroll
      for (int i = 0; i < 8; i++)
        ts[i] = (sacc[0][i] + sacc[0][i + 8]) + (sacc[1][i] + sacc[1][i + 8]);
#pragma unroll
      for (int i = 0; i < 4; i++) ts[i] += ts[i + 4];
      rs = (ts[0] + ts[2]) + (ts[1] + ts[3]);
    }
    l_i += xhalf_sum(rs);

    // ---- O^T += V^T P^T : in-register P (T12), 4 kv-chunks of 32x32x16
    // swap(w0,w2): r.x = low-kv word, r.y = high-kv word (R3-harness-verified)
    __builtin_amdgcn_s_setprio(1);
#pragma unroll
    for (int kvc = 0; kvc < 4; kvc++) {
      int ns = kvc >> 1, rb = (kvc & 1) * 8;
      int w0 = (int)pkbf(sacc[ns][rb + 0], sacc[ns][rb + 1]);
      int w1 = (int)pkbf(sacc[ns][rb + 2], sacc[ns][rb + 3]);
      int w2 = (int)pkbf(sacc[ns][rb + 4], sacc[ns][rb + 5]);
      int w3 = (int)pkbf(sacc[ns][rb + 6], sacc[ns][rb + 7]);
      i32x2 r02 = __builtin_amdgcn_permlane32_swap(w0, w2, false, false);
      i32x2 r13 = __builtin_amdgcn_permlane32_swap(w1, w3, false, false);
      union { unsigned int u[4]; bf16x8 v8; } bpu;
      bpu.u[0] = (unsigned int)r02.x; bpu.u[1] = (unsigned int)r13.x;
      bpu.u[2] = (unsigned int)r02.y; bpu.u[3] = (unsigned int)r13.y;
      bf16x8 bp = bpu.v8;
#pragma unroll
      for (int dt = 0; dt < 4; dt++)
        oacc[dt] = __builtin_amdgcn_mfma_f32_32x32x16_bf16(av[kvc * 4 + dt], bp, oacc[dt], 0, 0, 0);
    }
    __builtin_amdgcn_s_setprio(0);
  }

  // ---- epilogue: O^T -> per-wave LDS transpose -> global
  bf16_t* scr = scr_all[w];
  float inv = 1.f / l_i;
  int qr = lane >> 1, seg = lane & 1;
  int srow = s0 + w * 32 + qr;
#pragma unroll
  for (int half = 0; half < 2; half++) {
#pragma unroll
    for (int dl = 0; dl < 2; dl++) {
      int dt = half * 2 + dl;
#pragma unroll
      for (int tt = 0; tt < 4; tt++) {
        bf16x4 v;
#pragma unroll
        for (int r4 = 0; r4 < 4; r4++) v[r4] = (__bf16)(oacc[dt][tt * 4 + r4] * inv);
        int c8 = dl * 8 + 2 * tt + hh;          // d chunk (dl*32 + 8tt + 4hh)/4
        int pc8 = c8 ^ (l31 & 15);
        *(bf16x4*)&scr[l31 * 64 + pc8 * 4] = v;
      }
    }
    // same-wave DS ordering guarantees write->read visibility (per-wave region)
#pragma unroll
    for (int i = 0; i < 4; i++) {
      int c8 = seg * 8 + 2 * i;
      bf16x4 lo = *(const bf16x4*)&scr[qr * 64 + ((c8) ^ (qr & 15)) * 4];
      bf16x4 hi = *(const bf16x4*)&scr[qr * 64 + ((c8 + 1) ^ (qr & 15)) * 4];
      bf16x8 val;
#pragma unroll
      for (int j = 0; j < 4; j++) { val[j] = lo[j]; val[j + 4] = hi[j]; }
      if (srow < S_LEN)
        *(bf16x8*)&o[(size_t)srow * DIM + head * HD + half * 64 + seg * 32 + i * 8] = val;
    }
  }
}

// ---------------- launch ----------------

extern "C" void kernel_launch(void* const* d_in, const int* in_sizes, int n_in,
                              void* d_out, int out_size, void* d_ws, size_t ws_size,
                              hipStream_t stream) {
  const float* x    = (const float*)d_in[0];
  const float* q_w  = (const float*)d_in[1];
  const float* q_b  = (const float*)d_in[2];
  const float* k_w  = (const float*)d_in[3];
  const float* k_b  = (const float*)d_in[4];
  const float* v_w  = (const float*)d_in[5];
  const float* v_b  = (const float*)d_in[6];
  const float* o_w  = (const float*)d_in[7];
  const float* o_b  = (const float*)d_in[8];
  const float* nqw  = (const float*)d_in[9];
  const float* nkw  = (const float*)d_in[10];
  const float* fcos = (const float*)d_in[11];
  const float* fsin = (const float*)d_in[12];

  char* ws = (char*)d_ws;
  bf16_t* xb   = (bf16_t*)(ws + 0);          // 16,908,288 B
  bf16_t* wqkv = (bf16_t*)(ws + 16908288);   // 14,155,776 B
  bf16_t* wob  = (bf16_t*)(ws + 31064064);   //  4,718,592 B
  bf16_t* qkv  = (bf16_t*)(ws + 35782656);   // 50,724,864 B
  bf16_t* qb   = (bf16_t*)(ws + 86507520);   // 16,908,288 B
  bf16_t* kb   = (bf16_t*)(ws + 103415808);  // 16,908,288 B
  bf16_t* vtb  = (bf16_t*)(ws + 0);          // alias xb (dead after GEMM1); 12*128*5504*2 = 16,908,288 B exactly
  bf16_t* aob  = (bf16_t*)(ws + 35782656);   // alias qkv (dead after rope+transpose)

  cvt_x_kernel<<<(MPAD * DIM / 4 + 255) / 256, 256, 0, stream>>>(x, xb);
  cvt_wqkv_kernel<<<(NQKV * DIM / 4 + 255) / 256, 256, 0, stream>>>(q_w, k_w, v_w, wqkv);
  cvt_wo_kernel<<<(DIM * DIM / 4 + 255) / 256, 256, 0, stream>>>(o_w, wob);

  gemm_bt_kernel<true><<<dim3(NQKV / 128, MPAD / 128), 256, 0, stream>>>(
      xb, wqkv, qkv, q_b, k_b, v_b, MPAD, NQKV, DIM, MPAD);

  rope_qk_kernel<<<MPAD, 256, 0, stream>>>(qkv, nqw, nkw, fcos, fsin, qb, kb);
  v_transpose_kernel<<<dim3(SPAD / 64, NH), 256, 0, stream>>>(qkv, vtb);

  flash_attn_kernel<<<dim3((MPAD / 128) * NH), 256, 0, stream>>>(qb, kb, vtb, aob);

  gemm_bt_kernel<false><<<dim3(DIM / 128, MPAD / 128), 256, 0, stream>>>(
      aob, wob, d_out, o_b, o_b, o_b, MPAD, DIM, DIM, S_LEN);
}

// Round 7
// 769.515 us; speedup vs baseline: 1.5991x; 1.5991x over previous
//
#include <hip/hip_runtime.h>

#define DIM 1536
#define NH 12
#define HD 128
#define S_LEN 5400
#define SPAD 5504      // vt row stride (43*128)
#define MPAD 5504      // 43*128 (GEMM M tiles / flash q tiles)
#define NQKV 4608
#define EPS_NORM 1e-6f

typedef __bf16 bf16_t;
typedef __bf16 bf16x8 __attribute__((ext_vector_type(8)));
typedef __bf16 bf16x4 __attribute__((ext_vector_type(4)));
typedef __bf16 bf16x2 __attribute__((ext_vector_type(2)));
typedef float  f32x4  __attribute__((ext_vector_type(4)));
typedef float  f32x16 __attribute__((ext_vector_type(16)));
typedef int    i32x2  __attribute__((ext_vector_type(2)));

// async global->LDS, 16B per lane; LDS dest is wave-uniform base + lane*16
#define GLOAD_LDS16(gp, lp) __builtin_amdgcn_global_load_lds( \
    (__attribute__((address_space(1))) void*)(void*)(gp),     \
    (__attribute__((address_space(3))) void*)(lp), 16, 0, 0)

// pack two f32 -> bf16x2 word (compiler emits cvt_pk; don't hand-write asm, m240)
__device__ __forceinline__ unsigned int pkbf(float a, float b) {
  union { bf16x2 h; unsigned int u; } c;
  c.h[0] = (__bf16)a; c.h[1] = (__bf16)b;
  return c.u;
}

// cross-half (lane ^ 32) reduce via permlane32_swap BUILTIN (two modeled defs,
// no register-coalescing hazard; max/sum of the result pair is direction-agnostic)
__device__ __forceinline__ float xhalf_max(float x) {
  i32x2 r = __builtin_amdgcn_permlane32_swap(__float_as_int(x), __float_as_int(x),
                                             false, false);
  return fmaxf(__int_as_float(r.x), __int_as_float(r.y));
}
__device__ __forceinline__ float xhalf_sum(float x) {
  i32x2 r = __builtin_amdgcn_permlane32_swap(__float_as_int(x), __float_as_int(x),
                                             false, false);
  return __int_as_float(r.x) + __int_as_float(r.y);
}

// ---------------- conversion kernels ----------------

__global__ __launch_bounds__(256) void cvt_x_kernel(const float* __restrict__ x,
                                                    bf16_t* __restrict__ xb) {
  size_t base = ((size_t)blockIdx.x * 256 + threadIdx.x) * 4;
  if (base >= (size_t)MPAD * DIM) return;
  size_t row = base / DIM;
  float4 v = make_float4(0.f, 0.f, 0.f, 0.f);
  if (row < S_LEN) v = *(const float4*)&x[base];
  bf16x4 o; o[0] = (__bf16)v.x; o[1] = (__bf16)v.y; o[2] = (__bf16)v.z; o[3] = (__bf16)v.w;
  *(bf16x4*)&xb[base] = o;
}

__global__ __launch_bounds__(256) void cvt_wqkv_kernel(const float* __restrict__ qw,
                                                       const float* __restrict__ kw,
                                                       const float* __restrict__ vw,
                                                       bf16_t* __restrict__ wb) {
  size_t base = ((size_t)blockIdx.x * 256 + threadIdx.x) * 4;
  if (base >= (size_t)NQKV * DIM) return;
  int row = (int)(base / DIM);
  int col = (int)(base - (size_t)row * DIM);
  const float* src; int rr = row;
  if (rr >= 3072)      { src = vw; rr -= 3072; }
  else if (rr >= 1536) { src = kw; rr -= 1536; }
  else                 { src = qw; }
  float4 v = *(const float4*)&src[(size_t)rr * DIM + col];
  bf16x4 o; o[0] = (__bf16)v.x; o[1] = (__bf16)v.y; o[2] = (__bf16)v.z; o[3] = (__bf16)v.w;
  *(bf16x4*)&wb[base] = o;
}

__global__ __launch_bounds__(256) void cvt_wo_kernel(const float* __restrict__ w,
                                                     bf16_t* __restrict__ wb) {
  size_t base = ((size_t)blockIdx.x * 256 + threadIdx.x) * 4;
  if (base >= (size_t)DIM * DIM) return;
  float4 v = *(const float4*)&w[base];
  bf16x4 o; o[0] = (__bf16)v.x; o[1] = (__bf16)v.y; o[2] = (__bf16)v.z; o[3] = (__bf16)v.w;
  *(bf16x4*)&wb[base] = o;
}

// ---------------- GEMM: C[M,N] = A[M,K] @ B[N,K]^T + bias ----------------
// 2-phase pipeline: prefetch k-tile t+1 into buf^1 while computing buf.

template<bool OUT_BF16>
__global__ __launch_bounds__(256) void gemm_bt_kernel(
    const bf16_t* __restrict__ A, const bf16_t* __restrict__ B, void* __restrict__ C,
    const float* __restrict__ bias0, const float* __restrict__ bias1,
    const float* __restrict__ bias2, int M, int N, int K, int Mvalid) {
  __shared__ bf16_t As[2][128 * 32];
  __shared__ bf16_t Bs[2][128 * 32];
  int tid = threadIdx.x;
  int lane = tid & 63, wave = tid >> 6, quad = lane >> 4, l16 = lane & 15;
  int m0 = blockIdx.y * 128, n0 = blockIdx.x * 128;
  int wm = (wave >> 1) * 64, wn = (wave & 1) * 64;
  const bf16_t* Ab = A + (size_t)m0 * K;
  const bf16_t* Bb = B + (size_t)n0 * K;
  f32x4 acc[4][4] = {};

  int eo0 = tid * 8;
  int row0 = eo0 >> 5, col0 = eo0 & 31;
  int eo1 = (256 + tid) * 8;
  int row1 = eo1 >> 5, col1 = eo1 & 31;

  // prologue: stage k-tile 0 into buf 0
  GLOAD_LDS16(Ab + (size_t)row0 * K + col0, &As[0][eo0]);
  GLOAD_LDS16(Bb + (size_t)row0 * K + col0, &Bs[0][eo0]);
  GLOAD_LDS16(Ab + (size_t)row1 * K + col1, &As[0][eo1]);
  GLOAD_LDS16(Bb + (size_t)row1 * K + col1, &Bs[0][eo1]);
  asm volatile("s_waitcnt vmcnt(0)" ::: "memory");
  __builtin_amdgcn_s_barrier();
  __builtin_amdgcn_sched_barrier(0);

  int KT = K >> 5;
  for (int t = 0; t < KT; t++) {
    int cur = t & 1;
    if (t + 1 < KT) {
      int kn = (t + 1) << 5;
      GLOAD_LDS16(Ab + (size_t)row0 * K + kn + col0, &As[cur ^ 1][eo0]);
      GLOAD_LDS16(Bb + (size_t)row0 * K + kn + col0, &Bs[cur ^ 1][eo0]);
      GLOAD_LDS16(Ab + (size_t)row1 * K + kn + col1, &As[cur ^ 1][eo1]);
      GLOAD_LDS16(Bb + (size_t)row1 * K + kn + col1, &Bs[cur ^ 1][eo1]);
    }
    bf16x8 af[4], bfr[4];
#pragma unroll
    for (int i = 0; i < 4; i++)
      af[i] = *(const bf16x8*)&As[cur][(wm + i * 16 + l16) * 32 + quad * 8];
#pragma unroll
    for (int j = 0; j < 4; j++)
      bfr[j] = *(const bf16x8*)&Bs[cur][(wn + j * 16 + l16) * 32 + quad * 8];
#pragma unroll
    for (int i = 0; i < 4; i++)
#pragma unroll
      for (int j = 0; j < 4; j++)
        acc[i][j] = __builtin_amdgcn_mfma_f32_16x16x32_bf16(af[i], bfr[j], acc[i][j], 0, 0, 0);
    asm volatile("s_waitcnt vmcnt(0) lgkmcnt(0)" ::: "memory");
    __builtin_amdgcn_s_barrier();
    __builtin_amdgcn_sched_barrier(0);
  }
  // epilogue: C/D layout col=lane&15, row=quad*4+reg  [m89-verified]
#pragma unroll
  for (int j = 0; j < 4; j++) {
    int n = n0 + wn + j * 16 + l16;
    float bias = (n < 1536) ? bias0[n] : (n < 3072) ? bias1[n - 1536] : bias2[n - 3072];
#pragma unroll
    for (int i = 0; i < 4; i++) {
#pragma unroll
      for (int r = 0; r < 4; r++) {
        int m = m0 + wm + i * 16 + quad * 4 + r;
        float v = acc[i][j][r] + bias;
        if (OUT_BF16) {
          ((bf16_t*)C)[(size_t)m * N + n] = (__bf16)v;
        } else {
          if (m < Mvalid) ((float*)C)[(size_t)m * N + n] = v;
        }
      }
    }
  }
}

// ---------------- RMSNorm + RoPE for q,k ----------------
// q pre-scaled by (1/sqrt(HD)) * log2(e) so flash uses raw v_exp_f32 (2^x)
// with no per-element multiply and no logit scale.

__global__ __launch_bounds__(256) void rope_qk_kernel(
    const bf16_t* __restrict__ qkv, const float* __restrict__ nqw,
    const float* __restrict__ nkw, const float* __restrict__ fcos,
    const float* __restrict__ fsin, bf16_t* __restrict__ qout,
    bf16_t* __restrict__ kout) {
  int s = blockIdx.x;              // 0..MPAD-1
  int tid = threadIdx.x;
  bool valid = s < S_LEN;
  int f = s / 900, hh = (s / 30) % 30, ww = s % 30;
  __shared__ float red[4];
  for (int which = 0; which < 2; which++) {
    const bf16_t* src = qkv + (size_t)s * NQKV + which * DIM;
    const float* nw = which ? nkw : nqw;
    bf16_t* dst = (which ? kout : qout) + (size_t)s * DIM;
    // 0.12751742686 = (1/sqrt(128)) * log2(e)
    float osc = which ? 1.0f : 0.12751742686f;
    float v[6]; float ss = 0.f;
#pragma unroll
    for (int i = 0; i < 6; i++) {
      v[i] = valid ? (float)src[tid * 6 + i] : 0.f;
      ss += v[i] * v[i];
    }
#pragma unroll
    for (int off = 32; off >= 1; off >>= 1) ss += __shfl_down(ss, off);
    if ((tid & 63) == 0) red[tid >> 6] = ss;
    __syncthreads();
    float tot = red[0] + red[1] + red[2] + red[3];
    float rn = rsqrtf(tot * (1.f / DIM) + EPS_NORM);
    __syncthreads();   // protect red[] before next `which` iteration
#pragma unroll
    for (int i = 0; i < 3; i++) {
      int e0 = tid * 6 + 2 * i;
      int p = e0 >> 1;             // pair index; cc = p&63
      int cc = p & 63;
      int pos = (cc < 22) ? f : (cc < 43) ? hh : ww;  // split [22,21,21]
      float c = fcos[pos * 64 + cc], sn = fsin[pos * 64 + cc];
      float xr = v[2 * i] * rn * nw[e0];
      float xi = v[2 * i + 1] * rn * nw[e0 + 1];
      dst[e0]     = (__bf16)((xr * c - xi * sn) * osc);
      dst[e0 + 1] = (__bf16)((xr * sn + xi * c) * osc);
    }
  }
}

// ---------------- V transpose: qkv v-part -> vt[h][d][s] ----------------

__global__ __launch_bounds__(256) void v_transpose_kernel(const bf16_t* __restrict__ qkv,
                                                          bf16_t* __restrict__ vt) {
  __shared__ bf16_t tile[64][136];   // +8 pad
  int h = blockIdx.y, s0 = blockIdx.x * 64, tid = threadIdx.x;
#pragma unroll
  for (int it = 0; it < 4; it++) {
    int eo = (it * 256 + tid) * 8;   // 64x128 elements
    int row = eo >> 7, col = eo & 127;
    int s = s0 + row;
    bf16x8 val = {};
    if (s < S_LEN) val = *(const bf16x8*)&qkv[(size_t)s * NQKV + 3072 + h * HD + col];
    *(bf16x8*)&tile[row][col] = val;
  }
  __syncthreads();
  int d = tid & 127, j0 = (tid >> 7) * 32;
  bf16x8 outv[4];
#pragma unroll
  for (int b = 0; b < 4; b++)
#pragma unroll
    for (int j = 0; j < 8; j++) outv[b][j] = tile[j0 + b * 8 + j][d];
  size_t base = ((size_t)h * HD + d) * SPAD + s0 + j0;
#pragma unroll
  for (int b = 0; b < 4; b++) *(bf16x8*)&vt[base + b * 8] = outv[b];
}

// ---------------- flash attention (S^T = K Q^T, 32x32x16 MFMA) ----------------
// ONE-WAVE-BLOCK variant. Rationale: 516 4-wave blocks on 256 CUs gave 4 CUs
// 3 blocks and 252 CUs 2 -> wall time ~1.5x balanced (tail). 2064 one-wave
// blocks (64 thr) -> worst CU 9 waves vs 8 (tail 1.125x). Single-wave blocks
// need NO barriers (same-wave ordering + vmcnt/lgkmcnt), removing the ~20%
// barrier-wait class; blocks interleave freely per SIMD.
// Each block: 32 q-rows of one head; stages its own KVBLK=32 K/V tile in
// 16 KB LDS (gload_lds direct -> coalesced; R6 showed direct->VGPR frag loads
// fragment into 32B L2 transactions).
// Work mapping: 2064 items = 8 XCD chunks of 258 (bijective, m204).
// C/D 32x32 layout: col=lane&31, row=(reg&3)+8*(reg>>2)+4*(lane>>5)  [m74/m101]
// A/B frag: row/col=lane&31, k=(lane>>5)*8+j.

__global__ __launch_bounds__(64, 2) void flash_attn_kernel(
    const bf16_t* __restrict__ q, const bf16_t* __restrict__ k,
    const bf16_t* __restrict__ vt, bf16_t* __restrict__ o) {
  __shared__ __align__(16) bf16_t Ks[32 * 128];   // 8 KB: [kv 32][k 128], 16B chunk c at pc=c^(row&15)
  __shared__ __align__(16) bf16_t Vs[64 * 64];    // 8 KB: row r holds d=2r,2r+1; 8B chunk cp=(d&1)*4+(kv>>3), pc=cp^(r&7)
  int bid = blockIdx.x;
  int work = (bid & 7) * 258 + (bid >> 3);        // 2064 = 8*258 exactly
  int head = work / 172;
  int s0 = (work - head * 172) * 32;

  int lane = threadIdx.x;            // 0..63
  int l31 = lane & 31, hh = lane >> 5;

  // ---- Q B-frags (loop-invariant): B[col=q][k=16kc+8hh+j]
  bf16x8 bq[8];
  {
    const bf16_t* qp = &q[(size_t)(s0 + l31) * DIM + head * HD + hh * 8];
#pragma unroll
    for (int kc = 0; kc < 8; kc++) bq[kc] = *(const bf16x8*)(qp + kc * 16);
  }

  const bf16_t* kbase = k + (size_t)head * HD;
  const bf16_t* vbase = vt + (size_t)head * HD * SPAD;

  float m_i = -1e30f, l_i = 0.f;
  f32x16 oacc[4] = {};   // O^T: d = dt*32 + (r&3)+8*(r>>2)+4*hh, col q = l31

  const int NT = 169;    // 169*32 = 5408 >= 5400

  for (int t = 0; t < NT; t++) {
    int kt = t * 32;

    // ---- stage K tile 32 kv x 128 k (8 gload/lane)
#pragma unroll
    for (int it = 0; it < 8; it++) {
      int slot = it * 64 + lane;
      int row = slot >> 4, pc = slot & 15;
      int c = pc ^ (row & 15);
      GLOAD_LDS16(kbase + (size_t)(kt + row) * DIM + c * 8, &Ks[slot * 8]);
    }
    // ---- stage V^T tile 128 d x 32 kv (d-pair interleaved rows, 8 gload/lane)
#pragma unroll
    for (int it = 0; it < 8; it++) {
      int slot = it * 64 + lane;
      int row = slot >> 3, pc = slot & 7;
      int cp = pc ^ (row & 7);
      int d = 2 * row + (cp >> 2);
      GLOAD_LDS16(vbase + (size_t)d * SPAD + kt + (cp & 3) * 8, &Vs[slot * 8]);
    }
    asm volatile("s_waitcnt vmcnt(0)" ::: "memory");   // own loads -> LDS valid (single wave)
    __builtin_amdgcn_sched_barrier(0);

    // ---- S^T = K Q^T : 8 k-chunks of 32x32x16
    f32x16 sacc = {};
    __builtin_amdgcn_s_setprio(1);
#pragma unroll
    for (int kc = 0; kc < 8; kc++) {
      int pc = (kc * 2 + hh) ^ (l31 & 15);
      bf16x8 ak = *(const bf16x8*)&Ks[l31 * 128 + pc * 8];
      sacc = __builtin_amdgcn_mfma_f32_32x32x16_bf16(ak, bq[kc], sacc, 0, 0, 0);
    }
    __builtin_amdgcn_s_setprio(0);

    // ---- mask (final tile only)
    if (kt + 32 > S_LEN) {
#pragma unroll
      for (int r = 0; r < 16; r++) {
        int kvg = kt + (r & 3) + 8 * (r >> 2) + 4 * hh;
        if (kvg >= S_LEN) sacc[r] = -1e30f;
      }
    }

    // ---- online softmax (log2 domain), tree max, permlane cross-half
    float mx;
    {
      float tm[8];
#pragma unroll
      for (int i = 0; i < 8; i++) tm[i] = fmaxf(sacc[i], sacc[i + 8]);
#pragma unroll
      for (int i = 0; i < 4; i++) tm[i] = fmaxf(tm[i], tm[i + 4]);
      mx = fmaxf(fmaxf(tm[0], tm[2]), fmaxf(tm[1], tm[3]));
    }
    mx = xhalf_max(mx);
    if (!__all(mx - m_i <= 11.5f)) {   // 11.5 ~= 8*log2(e)
      float mn = fmaxf(m_i, mx);
      float al = __builtin_amdgcn_exp2f(m_i - mn);
      l_i *= al;
#pragma unroll
      for (int dt = 0; dt < 4; dt++)
#pragma unroll
        for (int r = 0; r < 16; r++) oacc[dt][r] *= al;
      m_i = mn;
    }
#pragma unroll
    for (int r = 0; r < 16; r++)
      sacc[r] = __builtin_amdgcn_exp2f(sacc[r] - m_i);
    float rs;
    {
      float ts[8];
#pragma unroll
      for (int i = 0; i < 8; i++) ts[i] = sacc[i] + sacc[i + 8];
#pragma unroll
      for (int i = 0; i < 4; i++) ts[i] += ts[i + 4];
      rs = (ts[0] + ts[2]) + (ts[1] + ts[3]);
    }
    l_i += xhalf_sum(rs);

    // ---- O^T += V^T P^T : in-register P (T12), 2 kv-chunks of 32x32x16
    // swap(w0,w2): r.x = low-kv word, r.y = high-kv word (R3-harness-verified)
    __builtin_amdgcn_s_setprio(1);
#pragma unroll
    for (int kvc = 0; kvc < 2; kvc++) {
      int rb = kvc * 8;
      int w0 = (int)pkbf(sacc[rb + 0], sacc[rb + 1]);
      int w1 = (int)pkbf(sacc[rb + 2], sacc[rb + 3]);
      int w2 = (int)pkbf(sacc[rb + 4], sacc[rb + 5]);
      int w3 = (int)pkbf(sacc[rb + 6], sacc[rb + 7]);
      i32x2 r02 = __builtin_amdgcn_permlane32_swap(w0, w2, false, false);
      i32x2 r13 = __builtin_amdgcn_permlane32_swap(w1, w3, false, false);
      union { unsigned int u[4]; bf16x8 v8; } bpu;
      bpu.u[0] = (unsigned int)r02.x; bpu.u[1] = (unsigned int)r13.x;
      bpu.u[2] = (unsigned int)r02.y; bpu.u[3] = (unsigned int)r13.y;
      bf16x8 bp = bpu.v8;
#pragma unroll
      for (int dt = 0; dt < 4; dt++) {
        int d = dt * 32 + l31;
        int r = d >> 1;
        int cp = ((d & 1) << 2) | (kvc * 2 + hh);
        int pc = cp ^ (r & 7);
        bf16x8 av = *(const bf16x8*)&Vs[r * 64 + pc * 8];
        oacc[dt] = __builtin_amdgcn_mfma_f32_32x32x16_bf16(av, bp, oacc[dt], 0, 0, 0);
      }
    }
    __builtin_amdgcn_s_setprio(0);

    // ---- own ds_reads retired before next stage overwrites (single wave)
    asm volatile("s_waitcnt lgkmcnt(0)" ::: "memory");
    __builtin_amdgcn_sched_barrier(0);
  }

  // ---- epilogue: O^T -> LDS transpose (scratch in dead Ks) -> global
  bf16_t* scr = Ks;   // 4 KB used
  float inv = 1.f / l_i;
  int qr = lane >> 1, seg = lane & 1;
  int srow = s0 + qr;
#pragma unroll
  for (int half = 0; half < 2; half++) {
#pragma unroll
    for (int dl = 0; dl < 2; dl++) {
      int dt = half * 2 + dl;
#pragma unroll
      for (int tt = 0; tt < 4; tt++) {
        bf16x4 v;
#pragma unroll
        for (int r4 = 0; r4 < 4; r4++) v[r4] = (__bf16)(oacc[dt][tt * 4 + r4] * inv);
        int c8 = dl * 8 + 2 * tt + hh;          // d chunk (dl*32 + 8tt + 4hh)/4
        int pc8 = c8 ^ (l31 & 15);
        *(bf16x4*)&scr[l31 * 64 + pc8 * 4] = v;
      }
    }
    // same-wave DS ordering guarantees write->read visibility
#pragma unroll
    for (int i = 0; i < 4; i++) {
      int c8 = seg * 8 + 2 * i;
      bf16x4 lo = *(const bf16x4*)&scr[qr * 64 + ((c8) ^ (qr & 15)) * 4];
      bf16x4 hi = *(const bf16x4*)&scr[qr * 64 + ((c8 + 1) ^ (qr & 15)) * 4];
      bf16x8 val;
#pragma unroll
      for (int j = 0; j < 4; j++) { val[j] = lo[j]; val[j + 4] = hi[j]; }
      if (srow < S_LEN)
        *(bf16x8*)&o[(size_t)srow * DIM + head * HD + half * 64 + seg * 32 + i * 8] = val;
    }
  }
}

// ---------------- launch ----------------

extern "C" void kernel_launch(void* const* d_in, const int* in_sizes, int n_in,
                              void* d_out, int out_size, void* d_ws, size_t ws_size,
                              hipStream_t stream) {
  const float* x    = (const float*)d_in[0];
  const float* q_w  = (const float*)d_in[1];
  const float* q_b  = (const float*)d_in[2];
  const float* k_w  = (const float*)d_in[3];
  const float* k_b  = (const float*)d_in[4];
  const float* v_w  = (const float*)d_in[5];
  const float* v_b  = (const float*)d_in[6];
  const float* o_w  = (const float*)d_in[7];
  const float* o_b  = (const float*)d_in[8];
  const float* nqw  = (const float*)d_in[9];
  const float* nkw  = (const float*)d_in[10];
  const float* fcos = (const float*)d_in[11];
  const float* fsin = (const float*)d_in[12];

  char* ws = (char*)d_ws;
  bf16_t* xb   = (bf16_t*)(ws + 0);          // 16,908,288 B
  bf16_t* wqkv = (bf16_t*)(ws + 16908288);   // 14,155,776 B
  bf16_t* wob  = (bf16_t*)(ws + 31064064);   //  4,718,592 B
  bf16_t* qkv  = (bf16_t*)(ws + 35782656);   // 50,724,864 B
  bf16_t* qb   = (bf16_t*)(ws + 86507520);   // 16,908,288 B
  bf16_t* kb   = (bf16_t*)(ws + 103415808);  // 16,908,288 B
  bf16_t* vtb  = (bf16_t*)(ws + 0);          // alias xb (dead after GEMM1); 12*128*5504*2 = 16,908,288 B exactly
  bf16_t* aob  = (bf16_t*)(ws + 35782656);   // alias qkv (dead after rope+transpose)

  cvt_x_kernel<<<(MPAD * DIM / 4 + 255) / 256, 256, 0, stream>>>(x, xb);
  cvt_wqkv_kernel<<<(NQKV * DIM / 4 + 255) / 256, 256, 0, stream>>>(q_w, k_w, v_w, wqkv);
  cvt_wo_kernel<<<(DIM * DIM / 4 + 255) / 256, 256, 0, stream>>>(o_w, wob);

  gemm_bt_kernel<true><<<dim3(NQKV / 128, MPAD / 128), 256, 0, stream>>>(
      xb, wqkv, qkv, q_b, k_b, v_b, MPAD, NQKV, DIM, MPAD);

  rope_qk_kernel<<<MPAD, 256, 0, stream>>>(qkv, nqw, nkw, fcos, fsin, qb, kb);
  v_transpose_kernel<<<dim3(SPAD / 64, NH), 256, 0, stream>>>(qkv, vtb);

  flash_attn_kernel<<<dim3(2064), 64, 0, stream>>>(qb, kb, vtb, aob);

  gemm_bt_kernel<false><<<dim3(DIM / 128, MPAD / 128), 256, 0, stream>>>(
      aob, wob, d_out, o_b, o_b, o_b, MPAD, DIM, DIM, S_LEN);
}

// Round 8
// 643.768 us; speedup vs baseline: 1.9114x; 1.1953x over previous
//
#include <hip/hip_runtime.h>

#define DIM 1536
#define NH 12
#define HD 128
#define S_LEN 5400
#define SPAD 5440      // 85*64  (flash kv tiles)
#define MPAD 5504      // 43*128 (flash q tiles / GEMM2 M)
#define MPAD2 5632     // 22*256 (GEMM1 M, padded)
#define NQKV 4608
#define EPS_NORM 1e-6f

typedef __bf16 bf16_t;
typedef __bf16 bf16x8 __attribute__((ext_vector_type(8)));
typedef __bf16 bf16x4 __attribute__((ext_vector_type(4)));
typedef __bf16 bf16x2 __attribute__((ext_vector_type(2)));
typedef float  f32x4  __attribute__((ext_vector_type(4)));
typedef float  f32x16 __attribute__((ext_vector_type(16)));
typedef int    i32x2  __attribute__((ext_vector_type(2)));

// async global->LDS, 16B per lane; LDS dest is wave-uniform base + lane*16
#define GLOAD_LDS16(gp, lp) __builtin_amdgcn_global_load_lds( \
    (__attribute__((address_space(1))) void*)(void*)(gp),     \
    (__attribute__((address_space(3))) void*)(lp), 16, 0, 0)

// pack two f32 -> bf16x2 word (compiler emits cvt_pk)
__device__ __forceinline__ unsigned int pkbf(float a, float b) {
  union { bf16x2 h; unsigned int u; } c;
  c.h[0] = (__bf16)a; c.h[1] = (__bf16)b;
  return c.u;
}

// cross-half (lane ^ 32) reduce via permlane32_swap BUILTIN
__device__ __forceinline__ float xhalf_max(float x) {
  i32x2 r = __builtin_amdgcn_permlane32_swap(__float_as_int(x), __float_as_int(x),
                                             false, false);
  return fmaxf(__int_as_float(r.x), __int_as_float(r.y));
}
__device__ __forceinline__ float xhalf_sum(float x) {
  i32x2 r = __builtin_amdgcn_permlane32_swap(__float_as_int(x), __float_as_int(x),
                                             false, false);
  return __int_as_float(r.x) + __int_as_float(r.y);
}

// ---------------- conversion kernels ----------------

__global__ __launch_bounds__(256) void cvt_x_kernel(const float* __restrict__ x,
                                                    bf16_t* __restrict__ xb) {
  size_t base = ((size_t)blockIdx.x * 256 + threadIdx.x) * 4;
  if (base >= (size_t)MPAD2 * DIM) return;
  size_t row = base / DIM;
  float4 v = make_float4(0.f, 0.f, 0.f, 0.f);
  if (row < S_LEN) v = *(const float4*)&x[base];
  bf16x4 o; o[0] = (__bf16)v.x; o[1] = (__bf16)v.y; o[2] = (__bf16)v.z; o[3] = (__bf16)v.w;
  *(bf16x4*)&xb[base] = o;
}

__global__ __launch_bounds__(256) void cvt_wqkv_kernel(const float* __restrict__ qw,
                                                       const float* __restrict__ kw,
                                                       const float* __restrict__ vw,
                                                       bf16_t* __restrict__ wb) {
  size_t base = ((size_t)blockIdx.x * 256 + threadIdx.x) * 4;
  if (base >= (size_t)NQKV * DIM) return;
  int row = (int)(base / DIM);
  int col = (int)(base - (size_t)row * DIM);
  const float* src; int rr = row;
  if (rr >= 3072)      { src = vw; rr -= 3072; }
  else if (rr >= 1536) { src = kw; rr -= 1536; }
  else                 { src = qw; }
  float4 v = *(const float4*)&src[(size_t)rr * DIM + col];
  bf16x4 o; o[0] = (__bf16)v.x; o[1] = (__bf16)v.y; o[2] = (__bf16)v.z; o[3] = (__bf16)v.w;
  *(bf16x4*)&wb[base] = o;
}

__global__ __launch_bounds__(256) void cvt_wo_kernel(const float* __restrict__ w,
                                                     bf16_t* __restrict__ wb) {
  size_t base = ((size_t)blockIdx.x * 256 + threadIdx.x) * 4;
  if (base >= (size_t)DIM * DIM) return;
  float4 v = *(const float4*)&w[base];
  bf16x4 o; o[0] = (__bf16)v.x; o[1] = (__bf16)v.y; o[2] = (__bf16)v.z; o[3] = (__bf16)v.w;
  *(bf16x4*)&wb[base] = o;
}

// ---------------- GEMM1: 256x256 tile, BK=64, 8 waves, 4-phase counted-vmcnt ----------------
// C[M,N] = A[M,K] @ B[N,K]^T + bias (bf16 out). M=5632, N=4608, K=1536.
// T3+T4 (m201-style): per K-tile 4 phases, each {vmcnt(N); barrier; ds_read
// frags; issue 2 stage-rounds of next tile; lgkmcnt(0); 16 MFMA}.
// Stage order per tile: B-q0,B-q1 | B-q2,B-q3 | A-q0,A-q2 | A-q1,A-q3
// -> waits vmcnt(2),(2),(4),(6); never drained in steady state.
// LDS layout [256 rows][8 chunks of 8 bf16], chunk c stored at pc=c^(row&7)
// (involution on source+read, linear gload dest; uniform 2-way banks = free).
// Barrier safety: lgkmcnt(0) precedes MFMA precedes next barrier arrival, so
// passing a phase's top barrier proves all waves' previous-phase ds_reads
// retired -> staging into the other buffer region is race-free.

__global__ __launch_bounds__(512, 2) void gemm1_256_kernel(
    const bf16_t* __restrict__ A, const bf16_t* __restrict__ B,
    bf16_t* __restrict__ C, const float* __restrict__ bias0,
    const float* __restrict__ bias1, const float* __restrict__ bias2) {
  const int K = 1536, N = NQKV, KT = 24;
  __shared__ bf16_t lds[2][2][256 * 64];   // [buf][A/B][row*64 + pc*8] = 128 KB
  int tid = threadIdx.x;
  int lane = tid & 63, wave = tid >> 6, quad = lane >> 4, l16 = lane & 15;
  int wm2 = wave >> 2, wn4 = wave & 3;     // wave owns rows wm2*128+[0,128), cols wn4*64+[0,64)
  int m0 = blockIdx.y * 256, n0 = blockIdx.x * 256;
  const bf16_t* Ab = A + (size_t)m0 * K;
  const bf16_t* Bb = B + (size_t)n0 * K;
  f32x4 acc[8][4] = {};

  int srow = tid >> 3, spc = tid & 7;           // staging: row-in-quarter, slot
  int ldst = srow * 64 + spc * 8;               // LDS elems within quarter base
  int sc8 = (spc ^ (srow & 7)) * 8;             // global k-chunk (inverse swz)

#define G1_STAGE(buf, op, q, kt) \
  GLOAD_LDS16((op ? Bb : Ab) + (size_t)((q) * 64 + srow) * K + (kt) + sc8, \
              &lds[buf][op][(q) * 64 * 64 + ldst])

  // prologue: tile 0 -> buf 0, rounds: B0 B1 B2 B3 A0 A2 A1 A3
  G1_STAGE(0, 1, 0, 0); G1_STAGE(0, 1, 1, 0);
  G1_STAGE(0, 1, 2, 0); G1_STAGE(0, 1, 3, 0);
  G1_STAGE(0, 0, 0, 0); G1_STAGE(0, 0, 2, 0);
  G1_STAGE(0, 0, 1, 0); G1_STAGE(0, 0, 3, 0);

  int pcq0 = (0 * 4 + quad) ^ (l16 & 7);        // chunk slots for kk=0/1
  int pcq1 = (1 * 4 + quad) ^ (l16 & 7);

  for (int t = 0; t < KT; t++) {
    int cur = t & 1, nxt = cur ^ 1;
    int kn = (t + 1) * 64;
    bool st = (t + 1 < KT);

#define G1_PHASE(mh, nh2, STAGES, WAITS)                                      \
    {                                                                         \
      WAITS;                                                                  \
      __builtin_amdgcn_s_barrier();                                           \
      __builtin_amdgcn_sched_barrier(0);                                      \
      bf16x8 af[4][2], bfv[2][2];                                             \
      _Pragma("unroll")                                                       \
      for (int i2 = 0; i2 < 4; i2++) {                                        \
        int row = wm2 * 128 + ((mh) * 4 + i2) * 16 + l16;                     \
        af[i2][0] = *(const bf16x8*)&lds[cur][0][row * 64 + pcq0 * 8];        \
        af[i2][1] = *(const bf16x8*)&lds[cur][0][row * 64 + pcq1 * 8];        \
      }                                                                       \
      _Pragma("unroll")                                                       \
      for (int j2 = 0; j2 < 2; j2++) {                                        \
        int rowb = wn4 * 64 + ((nh2) * 2 + j2) * 16 + l16;                    \
        bfv[j2][0] = *(const bf16x8*)&lds[cur][1][rowb * 64 + pcq0 * 8];      \
        bfv[j2][1] = *(const bf16x8*)&lds[cur][1][rowb * 64 + pcq1 * 8];      \
      }                                                                       \
      if (st) { STAGES; }                                                     \
      asm volatile("s_waitcnt lgkmcnt(0)" ::: "memory");                      \
      __builtin_amdgcn_sched_barrier(0);                                      \
      __builtin_amdgcn_s_setprio(1);                                          \
      _Pragma("unroll")                                                       \
      for (int i2 = 0; i2 < 4; i2++)                                          \
        _Pragma("unroll")                                                     \
        for (int j2 = 0; j2 < 2; j2++)                                        \
          _Pragma("unroll")                                                   \
          for (int kk = 0; kk < 2; kk++)                                      \
            acc[(mh) * 4 + i2][(nh2) * 2 + j2] =                              \
                __builtin_amdgcn_mfma_f32_16x16x32_bf16(                      \
                    af[i2][kk], bfv[j2][kk],                                  \
                    acc[(mh) * 4 + i2][(nh2) * 2 + j2], 0, 0, 0);             \
      __builtin_amdgcn_s_setprio(0);                                          \
    }

    G1_PHASE(0, 0, G1_STAGE(nxt,1,0,kn); G1_STAGE(nxt,1,1,kn),
             if (st) asm volatile("s_waitcnt vmcnt(2)" ::: "memory");
             else    asm volatile("s_waitcnt vmcnt(0)" ::: "memory"));
    G1_PHASE(1, 0, G1_STAGE(nxt,1,2,kn); G1_STAGE(nxt,1,3,kn),
             if (st) asm volatile("s_waitcnt vmcnt(2)" ::: "memory");
             else    asm volatile("s_waitcnt vmcnt(0)" ::: "memory"));
    G1_PHASE(0, 1, G1_STAGE(nxt,0,0,kn); G1_STAGE(nxt,0,2,kn),
             asm volatile("s_waitcnt vmcnt(4)" ::: "memory"));
    G1_PHASE(1, 1, G1_STAGE(nxt,0,1,kn); G1_STAGE(nxt,0,3,kn),
             asm volatile("s_waitcnt vmcnt(6)" ::: "memory"));
#undef G1_PHASE
  }
#undef G1_STAGE

  // epilogue: C/D layout col=lane&15, row=quad*4+reg  [m89-verified]
#pragma unroll
  for (int j = 0; j < 4; j++) {
    int n = n0 + wn4 * 64 + j * 16 + l16;
    float bias = (n < 1536) ? bias0[n] : (n < 3072) ? bias1[n - 1536] : bias2[n - 3072];
#pragma unroll
    for (int i = 0; i < 8; i++) {
#pragma unroll
      for (int r = 0; r < 4; r++) {
        int m = m0 + wm2 * 128 + i * 16 + quad * 4 + r;
        C[(size_t)m * N + n] = (__bf16)(acc[i][j][r] + bias);
      }
    }
  }
}

// ---------------- GEMM2 (128-tile, known-good): C = A @ B^T + bias ----------------

template<bool OUT_BF16>
__global__ __launch_bounds__(256) void gemm_bt_kernel(
    const bf16_t* __restrict__ A, const bf16_t* __restrict__ B, void* __restrict__ C,
    const float* __restrict__ bias0, const float* __restrict__ bias1,
    const float* __restrict__ bias2, int M, int N, int K, int Mvalid) {
  __shared__ bf16_t As[2][128 * 32];
  __shared__ bf16_t Bs[2][128 * 32];
  int tid = threadIdx.x;
  int lane = tid & 63, wave = tid >> 6, quad = lane >> 4, l16 = lane & 15;
  int m0 = blockIdx.y * 128, n0 = blockIdx.x * 128;
  int wm = (wave >> 1) * 64, wn = (wave & 1) * 64;
  const bf16_t* Ab = A + (size_t)m0 * K;
  const bf16_t* Bb = B + (size_t)n0 * K;
  f32x4 acc[4][4] = {};

  int eo0 = tid * 8;
  int row0 = eo0 >> 5, col0 = eo0 & 31;
  int eo1 = (256 + tid) * 8;
  int row1 = eo1 >> 5, col1 = eo1 & 31;

  GLOAD_LDS16(Ab + (size_t)row0 * K + col0, &As[0][eo0]);
  GLOAD_LDS16(Bb + (size_t)row0 * K + col0, &Bs[0][eo0]);
  GLOAD_LDS16(Ab + (size_t)row1 * K + col1, &As[0][eo1]);
  GLOAD_LDS16(Bb + (size_t)row1 * K + col1, &Bs[0][eo1]);
  asm volatile("s_waitcnt vmcnt(0)" ::: "memory");
  __builtin_amdgcn_s_barrier();
  __builtin_amdgcn_sched_barrier(0);

  int KT = K >> 5;
  for (int t = 0; t < KT; t++) {
    int cur = t & 1;
    if (t + 1 < KT) {
      int kn = (t + 1) << 5;
      GLOAD_LDS16(Ab + (size_t)row0 * K + kn + col0, &As[cur ^ 1][eo0]);
      GLOAD_LDS16(Bb + (size_t)row0 * K + kn + col0, &Bs[cur ^ 1][eo0]);
      GLOAD_LDS16(Ab + (size_t)row1 * K + kn + col1, &As[cur ^ 1][eo1]);
      GLOAD_LDS16(Bb + (size_t)row1 * K + kn + col1, &Bs[cur ^ 1][eo1]);
    }
    bf16x8 af[4], bfr[4];
#pragma unroll
    for (int i = 0; i < 4; i++)
      af[i] = *(const bf16x8*)&As[cur][(wm + i * 16 + l16) * 32 + quad * 8];
#pragma unroll
    for (int j = 0; j < 4; j++)
      bfr[j] = *(const bf16x8*)&Bs[cur][(wn + j * 16 + l16) * 32 + quad * 8];
#pragma unroll
    for (int i = 0; i < 4; i++)
#pragma unroll
      for (int j = 0; j < 4; j++)
        acc[i][j] = __builtin_amdgcn_mfma_f32_16x16x32_bf16(af[i], bfr[j], acc[i][j], 0, 0, 0);
    asm volatile("s_waitcnt vmcnt(0) lgkmcnt(0)" ::: "memory");
    __builtin_amdgcn_s_barrier();
    __builtin_amdgcn_sched_barrier(0);
  }
#pragma unroll
  for (int j = 0; j < 4; j++) {
    int n = n0 + wn + j * 16 + l16;
    float bias = (n < 1536) ? bias0[n] : (n < 3072) ? bias1[n - 1536] : bias2[n - 3072];
#pragma unroll
    for (int i = 0; i < 4; i++) {
#pragma unroll
      for (int r = 0; r < 4; r++) {
        int m = m0 + wm + i * 16 + quad * 4 + r;
        float v = acc[i][j][r] + bias;
        if (OUT_BF16) {
          ((bf16_t*)C)[(size_t)m * N + n] = (__bf16)v;
        } else {
          if (m < Mvalid) ((float*)C)[(size_t)m * N + n] = v;
        }
      }
    }
  }
}

// ---------------- RMSNorm + RoPE for q,k ----------------
// q pre-scaled by (1/sqrt(HD)) * log2(e) so flash uses raw v_exp_f32 (2^x).

__global__ __launch_bounds__(256) void rope_qk_kernel(
    const bf16_t* __restrict__ qkv, const float* __restrict__ nqw,
    const float* __restrict__ nkw, const float* __restrict__ fcos,
    const float* __restrict__ fsin, bf16_t* __restrict__ qout,
    bf16_t* __restrict__ kout) {
  int s = blockIdx.x;              // 0..MPAD-1
  int tid = threadIdx.x;
  bool valid = s < S_LEN;
  int f = s / 900, hh = (s / 30) % 30, ww = s % 30;
  __shared__ float red[4];
  for (int which = 0; which < 2; which++) {
    const bf16_t* src = qkv + (size_t)s * NQKV + which * DIM;
    const float* nw = which ? nkw : nqw;
    bf16_t* dst = (which ? kout : qout) + (size_t)s * DIM;
    // 0.12751742686 = (1/sqrt(128)) * log2(e)
    float osc = which ? 1.0f : 0.12751742686f;
    float v[6]; float ss = 0.f;
#pragma unroll
    for (int i = 0; i < 6; i++) {
      v[i] = valid ? (float)src[tid * 6 + i] : 0.f;
      ss += v[i] * v[i];
    }
#pragma unroll
    for (int off = 32; off >= 1; off >>= 1) ss += __shfl_down(ss, off);
    if ((tid & 63) == 0) red[tid >> 6] = ss;
    __syncthreads();
    float tot = red[0] + red[1] + red[2] + red[3];
    float rn = rsqrtf(tot * (1.f / DIM) + EPS_NORM);
    __syncthreads();   // protect red[] before next `which` iteration
#pragma unroll
    for (int i = 0; i < 3; i++) {
      int e0 = tid * 6 + 2 * i;
      int p = e0 >> 1;
      int cc = p & 63;
      int pos = (cc < 22) ? f : (cc < 43) ? hh : ww;  // split [22,21,21]
      float c = fcos[pos * 64 + cc], sn = fsin[pos * 64 + cc];
      float xr = v[2 * i] * rn * nw[e0];
      float xi = v[2 * i + 1] * rn * nw[e0 + 1];
      dst[e0]     = (__bf16)((xr * c - xi * sn) * osc);
      dst[e0 + 1] = (__bf16)((xr * sn + xi * c) * osc);
    }
  }
}

// ---------------- V transpose: qkv v-part -> vt[h][d][s] ----------------

__global__ __launch_bounds__(256) void v_transpose_kernel(const bf16_t* __restrict__ qkv,
                                                          bf16_t* __restrict__ vt) {
  __shared__ bf16_t tile[64][136];   // +8 pad
  int h = blockIdx.y, s0 = blockIdx.x * 64, tid = threadIdx.x;
#pragma unroll
  for (int it = 0; it < 4; it++) {
    int eo = (it * 256 + tid) * 8;   // 64x128 elements
    int row = eo >> 7, col = eo & 127;
    int s = s0 + row;
    bf16x8 val = {};
    if (s < S_LEN) val = *(const bf16x8*)&qkv[(size_t)s * NQKV + 3072 + h * HD + col];
    *(bf16x8*)&tile[row][col] = val;
  }
  __syncthreads();
  int d = tid & 127, j0 = (tid >> 7) * 32;
  bf16x8 outv[4];
#pragma unroll
  for (int b = 0; b < 4; b++)
#pragma unroll
    for (int j = 0; j < 8; j++) outv[b][j] = tile[j0 + b * 8 + j][d];
  size_t base = ((size_t)h * HD + d) * SPAD + s0 + j0;
#pragma unroll
  for (int b = 0; b < 4; b++) *(bf16x8*)&vt[base + b * 8] = outv[b];
}

// ---------------- flash attention (R3-exact: best measured 334.6 us) ----------------
// S^T = K Q^T with 32x32x16 MFMA; 2-phase dbuf K/V staging; in-register P
// (T12 cvt_pk + permlane32_swap builtin); log2-domain softmax with defer-max.
// C/D 32x32 layout: col=lane&31, row=(reg&3)+8*(reg>>2)+4*(lane>>5)  [m74/m101]

__global__ __launch_bounds__(256, 2) void flash_attn_kernel(
    const bf16_t* __restrict__ q, const bf16_t* __restrict__ k,
    const bf16_t* __restrict__ vt, bf16_t* __restrict__ o) {
  __shared__ bf16_t Ks[2][64 * 128];
  __shared__ bf16_t Vs[2][64 * 128];
  int head = blockIdx.y;
  int s0 = blockIdx.x * 128;
  int tid = threadIdx.x, w = tid >> 6, lane = tid & 63;
  int l31 = lane & 31, hh = lane >> 5;

  bf16x8 bq[8];
  {
    const bf16_t* qp = &q[(size_t)(s0 + w * 32 + l31) * DIM + head * HD + hh * 8];
#pragma unroll
    for (int kc = 0; kc < 8; kc++) bq[kc] = *(const bf16x8*)(qp + kc * 16);
  }

  float m_i = -1e30f, l_i = 0.f;
  f32x16 oacc[4] = {};

  const int NT = SPAD / 64;   // 85

#pragma unroll
  for (int it = 0; it < 4; it++) {
    int slot = it * 256 + tid;
    int row = slot >> 4, pc = slot & 15;
    int c = pc ^ (row & 15);
    GLOAD_LDS16(k + (size_t)row * DIM + head * HD + c * 8, &Ks[0][slot * 8]);
  }
#pragma unroll
  for (int it = 0; it < 4; it++) {
    int slot = it * 256 + tid;
    int row = slot >> 4, pc = slot & 15;
    int cp = pc ^ (row & 15);
    int d = 2 * row + (cp >> 3);
    GLOAD_LDS16(vt + ((size_t)head * HD + d) * SPAD + (cp & 7) * 8, &Vs[0][slot * 8]);
  }
  asm volatile("s_waitcnt vmcnt(0)" ::: "memory");
  __builtin_amdgcn_s_barrier();
  __builtin_amdgcn_sched_barrier(0);

  for (int t = 0; t < NT; t++) {
    int kt = t * 64;
    int cur = t & 1;

    if (t + 1 < NT) {
      int kn = kt + 64;
#pragma unroll
      for (int it = 0; it < 4; it++) {
        int slot = it * 256 + tid;
        int row = slot >> 4, pc = slot & 15;
        int c = pc ^ (row & 15);
        GLOAD_LDS16(k + (size_t)(kn + row) * DIM + head * HD + c * 8, &Ks[cur ^ 1][slot * 8]);
      }
#pragma unroll
      for (int it = 0; it < 4; it++) {
        int slot = it * 256 + tid;
        int row = slot >> 4, pc = slot & 15;
        int cp = pc ^ (row & 15);
        int d = 2 * row + (cp >> 3);
        GLOAD_LDS16(vt + ((size_t)head * HD + d) * SPAD + kn + (cp & 7) * 8, &Vs[cur ^ 1][slot * 8]);
      }
    }

    f32x16 sacc[2] = {};
    __builtin_amdgcn_s_setprio(1);
#pragma unroll
    for (int ns = 0; ns < 2; ns++) {
      int row = ns * 32 + l31;
#pragma unroll
      for (int kc = 0; kc < 8; kc++) {
        int pc = (kc * 2 + hh) ^ (row & 15);
        bf16x8 ak = *(const bf16x8*)&Ks[cur][row * 128 + pc * 8];
        sacc[ns] = __builtin_amdgcn_mfma_f32_32x32x16_bf16(ak, bq[kc], sacc[ns], 0, 0, 0);
      }
    }
    __builtin_amdgcn_s_setprio(0);

    if (kt + 64 > S_LEN) {
#pragma unroll
      for (int ns = 0; ns < 2; ns++)
#pragma unroll
        for (int r = 0; r < 16; r++) {
          int kvg = kt + ns * 32 + (r & 3) + 8 * (r >> 2) + 4 * hh;
          if (kvg >= S_LEN) sacc[ns][r] = -1e30f;
        }
    }

    float mx;
    {
      float tm[8];
#pragma unroll
      for (int i = 0; i < 8; i++)
        tm[i] = fmaxf(fmaxf(sacc[0][i], sacc[0][i + 8]),
                      fmaxf(sacc[1][i], sacc[1][i + 8]));
#pragma unroll
      for (int i = 0; i < 4; i++) tm[i] = fmaxf(tm[i], tm[i + 4]);
      mx = fmaxf(fmaxf(tm[0], tm[2]), fmaxf(tm[1], tm[3]));
    }
    mx = xhalf_max(mx);
    if (!__all(mx - m_i <= 11.5f)) {   // 11.5 ~= 8*log2(e)
      float mn = fmaxf(m_i, mx);
      float al = __builtin_amdgcn_exp2f(m_i - mn);
      l_i *= al;
#pragma unroll
      for (int dt = 0; dt < 4; dt++)
#pragma unroll
        for (int r = 0; r < 16; r++) oacc[dt][r] *= al;
      m_i = mn;
    }
#pragma unroll
    for (int ns = 0; ns < 2; ns++)
#pragma unroll
      for (int r = 0; r < 16; r++)
        sacc[ns][r] = __builtin_amdgcn_exp2f(sacc[ns][r] - m_i);
    float rs;
    {
      float ts[8];
#pragma unroll
      for (int i = 0; i < 8; i++)
        ts[i] = (sacc[0][i] + sacc[0][i + 8]) + (sacc[1][i] + sacc[1][i + 8]);
#pragma unroll
      for (int i = 0; i < 4; i++) ts[i] += ts[i + 4];
      rs = (ts[0] + ts[2]) + (ts[1] + ts[3]);
    }
    l_i += xhalf_sum(rs);

    __builtin_amdgcn_s_setprio(1);
#pragma unroll
    for (int kvc = 0; kvc < 4; kvc++) {
      int ns = kvc >> 1, rb = (kvc & 1) * 8;
      int w0 = (int)pkbf(sacc[ns][rb + 0], sacc[ns][rb + 1]);
      int w1 = (int)pkbf(sacc[ns][rb + 2], sacc[ns][rb + 3]);
      int w2 = (int)pkbf(sacc[ns][rb + 4], sacc[ns][rb + 5]);
      int w3 = (int)pkbf(sacc[ns][rb + 6], sacc[ns][rb + 7]);
      i32x2 r02 = __builtin_amdgcn_permlane32_swap(w0, w2, false, false);
      i32x2 r13 = __builtin_amdgcn_permlane32_swap(w1, w3, false, false);
      union { unsigned int u[4]; bf16x8 v8; } bpu;
      bpu.u[0] = (unsigned int)r02.x; bpu.u[1] = (unsigned int)r13.x;
      bpu.u[2] = (unsigned int)r02.y; bpu.u[3] = (unsigned int)r13.y;
      bf16x8 bp = bpu.v8;
#pragma unroll
      for (int dt = 0; dt < 4; dt++) {
        int d = dt * 32 + l31;
        int r = d >> 1;
        int cp = ((d & 1) << 3) | (kvc * 2 + hh);
        int pc = cp ^ (r & 15);
        bf16x8 av = *(const bf16x8*)&Vs[cur][r * 128 + pc * 8];
        oacc[dt] = __builtin_amdgcn_mfma_f32_32x32x16_bf16(av, bp, oacc[dt], 0, 0, 0);
      }
    }
    __builtin_amdgcn_s_setprio(0);

    asm volatile("s_waitcnt vmcnt(0) lgkmcnt(0)" ::: "memory");
    __builtin_amdgcn_s_barrier();
    __builtin_amdgcn_sched_barrier(0);
  }

  bf16_t* scr = ((bf16_t*)Ks) + w * (32 * 64);
  float inv = 1.f / l_i;
  int qr = lane >> 1, seg = lane & 1;
  int srow = s0 + w * 32 + qr;
#pragma unroll
  for (int half = 0; half < 2; half++) {
#pragma unroll
    for (int dl = 0; dl < 2; dl++) {
      int dt = half * 2 + dl;
#pragma unroll
      for (int tt = 0; tt < 4; tt++) {
        bf16x4 v;
#pragma unroll
        for (int r4 = 0; r4 < 4; r4++) v[r4] = (__bf16)(oacc[dt][tt * 4 + r4] * inv);
        int c8 = dl * 8 + 2 * tt + hh;
        int pc8 = c8 ^ (l31 & 15);
        *(bf16x4*)&scr[l31 * 64 + pc8 * 4] = v;
      }
    }
#pragma unroll
    for (int i = 0; i < 4; i++) {
      int c8 = seg * 8 + 2 * i;
      bf16x4 lo = *(const bf16x4*)&scr[qr * 64 + ((c8) ^ (qr & 15)) * 4];
      bf16x4 hi = *(const bf16x4*)&scr[qr * 64 + ((c8 + 1) ^ (qr & 15)) * 4];
      bf16x8 val;
#pragma unroll
      for (int j = 0; j < 4; j++) { val[j] = lo[j]; val[j + 4] = hi[j]; }
      if (srow < S_LEN)
        *(bf16x8*)&o[(size_t)srow * DIM + head * HD + half * 64 + seg * 32 + i * 8] = val;
    }
  }
}

// ---------------- launch ----------------

extern "C" void kernel_launch(void* const* d_in, const int* in_sizes, int n_in,
                              void* d_out, int out_size, void* d_ws, size_t ws_size,
                              hipStream_t stream) {
  const float* x    = (const float*)d_in[0];
  const float* q_w  = (const float*)d_in[1];
  const float* q_b  = (const float*)d_in[2];
  const float* k_w  = (const float*)d_in[3];
  const float* k_b  = (const float*)d_in[4];
  const float* v_w  = (const float*)d_in[5];
  const float* v_b  = (const float*)d_in[6];
  const float* o_w  = (const float*)d_in[7];
  const float* o_b  = (const float*)d_in[8];
  const float* nqw  = (const float*)d_in[9];
  const float* nkw  = (const float*)d_in[10];
  const float* fcos = (const float*)d_in[11];
  const float* fsin = (const float*)d_in[12];

  char* ws = (char*)d_ws;
  bf16_t* xb   = (bf16_t*)(ws + 0);           // 5632*1536*2 = 17,301,504
  bf16_t* wqkv = (bf16_t*)(ws + 17301504);    // 14,155,776
  bf16_t* wob  = (bf16_t*)(ws + 31457280);    //  4,718,592
  bf16_t* qkv  = (bf16_t*)(ws + 36175872);    // 5632*4608*2 = 51,904,512
  bf16_t* qb   = (bf16_t*)(ws + 88080384);    // 16,908,288
  bf16_t* kb   = (bf16_t*)(ws + 104988672);   // 16,908,288 (end ~121.9 MB)
  bf16_t* vtb  = (bf16_t*)(ws + 0);           // alias xb (dead after GEMM1); 12*128*5440*2 = 16,711,680
  bf16_t* aob  = (bf16_t*)(ws + 36175872);    // alias qkv (dead after rope+transpose)

  cvt_x_kernel<<<(MPAD2 * DIM / 4 + 255) / 256, 256, 0, stream>>>(x, xb);
  cvt_wqkv_kernel<<<(NQKV * DIM / 4 + 255) / 256, 256, 0, stream>>>(q_w, k_w, v_w, wqkv);
  cvt_wo_kernel<<<(DIM * DIM / 4 + 255) / 256, 256, 0, stream>>>(o_w, wob);

  gemm1_256_kernel<<<dim3(NQKV / 256, MPAD2 / 256), 512, 0, stream>>>(
      xb, wqkv, qkv, q_b, k_b, v_b);

  rope_qk_kernel<<<MPAD, 256, 0, stream>>>(qkv, nqw, nkw, fcos, fsin, qb, kb);
  v_transpose_kernel<<<dim3(SPAD / 64, NH), 256, 0, stream>>>(qkv, vtb);

  flash_attn_kernel<<<dim3(MPAD / 128, NH), 256, 0, stream>>>(qb, kb, vtb, aob);

  gemm_bt_kernel<false><<<dim3(DIM / 128, MPAD / 128), 256, 0, stream>>>(
      aob, wob, d_out, o_b, o_b, o_b, MPAD, DIM, DIM, S_LEN);
}

// Round 9
// 631.107 us; speedup vs baseline: 1.9498x; 1.0201x over previous
//
#include <hip/hip_runtime.h>

#define DIM 1536
#define NH 12
#define HD 128
#define S_LEN 5400
#define SPAD 5440      // 85*64  (flash kv tiles / vt col stride)
#define MPAD 5504      // 43*128 (flash q tiles / GEMM2 M)
#define MPAD2 5632     // 22*256 (GEMM1 M, padded)
#define NQKV 4608
#define EPS_NORM 1e-6f

typedef __bf16 bf16_t;
typedef __bf16 bf16x8 __attribute__((ext_vector_type(8)));
typedef __bf16 bf16x4 __attribute__((ext_vector_type(4)));
typedef __bf16 bf16x2 __attribute__((ext_vector_type(2)));
typedef float  f32x4  __attribute__((ext_vector_type(4)));
typedef float  f32x16 __attribute__((ext_vector_type(16)));
typedef int    i32x2  __attribute__((ext_vector_type(2)));

// async global->LDS, 16B per lane; LDS dest is wave-uniform base + lane*16
#define GLOAD_LDS16(gp, lp) __builtin_amdgcn_global_load_lds( \
    (__attribute__((address_space(1))) void*)(void*)(gp),     \
    (__attribute__((address_space(3))) void*)(lp), 16, 0, 0)

// pack two f32 -> bf16x2 word (compiler emits cvt_pk)
__device__ __forceinline__ unsigned int pkbf(float a, float b) {
  union { bf16x2 h; unsigned int u; } c;
  c.h[0] = (__bf16)a; c.h[1] = (__bf16)b;
  return c.u;
}

// cross-half (lane ^ 32) reduce via permlane32_swap BUILTIN
__device__ __forceinline__ float xhalf_max(float x) {
  i32x2 r = __builtin_amdgcn_permlane32_swap(__float_as_int(x), __float_as_int(x),
                                             false, false);
  return fmaxf(__int_as_float(r.x), __int_as_float(r.y));
}
__device__ __forceinline__ float xhalf_sum(float x) {
  i32x2 r = __builtin_amdgcn_permlane32_swap(__float_as_int(x), __float_as_int(x),
                                             false, false);
  return __int_as_float(r.x) + __int_as_float(r.y);
}

// ---------------- merged conversion kernel (3-in-1, saves 2 launches) ----------------
// block ranges: [0,8448) x->xb ; [8448,15360) qkv weights ; [15360,17664) o weight

#define CVT_NX 8448    // MPAD2*DIM/4/256
#define CVT_NW 6912    // NQKV*DIM/4/256
#define CVT_NO 2304    // DIM*DIM/4/256

__global__ __launch_bounds__(256) void cvt_all_kernel(
    const float* __restrict__ x, const float* __restrict__ qw,
    const float* __restrict__ kw, const float* __restrict__ vw,
    const float* __restrict__ ow, bf16_t* __restrict__ xb,
    bf16_t* __restrict__ wqkv, bf16_t* __restrict__ wob) {
  int b = blockIdx.x;
  if (b < CVT_NX) {
    size_t base = ((size_t)b * 256 + threadIdx.x) * 4;
    size_t row = base / DIM;
    float4 v = make_float4(0.f, 0.f, 0.f, 0.f);
    if (row < S_LEN) v = *(const float4*)&x[base];
    bf16x4 o; o[0] = (__bf16)v.x; o[1] = (__bf16)v.y; o[2] = (__bf16)v.z; o[3] = (__bf16)v.w;
    *(bf16x4*)&xb[base] = o;
  } else if (b < CVT_NX + CVT_NW) {
    size_t base = ((size_t)(b - CVT_NX) * 256 + threadIdx.x) * 4;
    int row = (int)(base / DIM);
    int col = (int)(base - (size_t)row * DIM);
    const float* src; int rr = row;
    if (rr >= 3072)      { src = vw; rr -= 3072; }
    else if (rr >= 1536) { src = kw; rr -= 1536; }
    else                 { src = qw; }
    float4 v = *(const float4*)&src[(size_t)rr * DIM + col];
    bf16x4 o; o[0] = (__bf16)v.x; o[1] = (__bf16)v.y; o[2] = (__bf16)v.z; o[3] = (__bf16)v.w;
    *(bf16x4*)&wqkv[base] = o;
  } else {
    size_t base = ((size_t)(b - CVT_NX - CVT_NW) * 256 + threadIdx.x) * 4;
    float4 v = *(const float4*)&ow[base];
    bf16x4 o; o[0] = (__bf16)v.x; o[1] = (__bf16)v.y; o[2] = (__bf16)v.z; o[3] = (__bf16)v.w;
    *(bf16x4*)&wob[base] = o;
  }
}

// ---------------- GEMM1: 256x256 tile, BK=64, 8 waves, 4-phase counted-vmcnt ----------------
// C[M,N] = A[M,K] @ B[N,K]^T + bias. M=5632, N=4608, K=1536.
// q,k output blocks (n0 < 3072) -> qkv[m][n] bf16.
// v output blocks (n0 >= 3072) -> FUSED transpose: vt[(h*HD+d)*SPAD + m]
//   (replaces v_transpose kernel; zero-fills m in [S_LEN, SPAD)).
// Schedule: T3+T4 per K-tile, 4 phases {vmcnt(N); barrier; ds_read frags;
// issue 2 stage-rounds of next tile; lgkmcnt(0); 16 MFMA}; stage order
// B0,B1|B2,B3|A0,A2|A1,A3 -> waits vmcnt(2),(2),(4),(6). LDS chunk swizzle
// pc=c^(row&7) on source+read, linear gload dest.

__global__ __launch_bounds__(512, 2) void gemm1_256_kernel(
    const bf16_t* __restrict__ A, const bf16_t* __restrict__ B,
    bf16_t* __restrict__ C, bf16_t* __restrict__ vt,
    const float* __restrict__ bias0, const float* __restrict__ bias1,
    const float* __restrict__ bias2) {
  const int K = 1536, N = NQKV, KT = 24;
  __shared__ bf16_t lds[2][2][256 * 64];   // [buf][A/B][row*64 + pc*8] = 128 KB
  int tid = threadIdx.x;
  int lane = tid & 63, wave = tid >> 6, quad = lane >> 4, l16 = lane & 15;
  int wm2 = wave >> 2, wn4 = wave & 3;
  int m0 = blockIdx.y * 256, n0 = blockIdx.x * 256;
  const bf16_t* Ab = A + (size_t)m0 * K;
  const bf16_t* Bb = B + (size_t)n0 * K;
  f32x4 acc[8][4] = {};

  int srow = tid >> 3, spc = tid & 7;
  int ldst = srow * 64 + spc * 8;
  int sc8 = (spc ^ (srow & 7)) * 8;

#define G1_STAGE(buf, op, q, kt) \
  GLOAD_LDS16((op ? Bb : Ab) + (size_t)((q) * 64 + srow) * K + (kt) + sc8, \
              &lds[buf][op][(q) * 64 * 64 + ldst])

  G1_STAGE(0, 1, 0, 0); G1_STAGE(0, 1, 1, 0);
  G1_STAGE(0, 1, 2, 0); G1_STAGE(0, 1, 3, 0);
  G1_STAGE(0, 0, 0, 0); G1_STAGE(0, 0, 2, 0);
  G1_STAGE(0, 0, 1, 0); G1_STAGE(0, 0, 3, 0);

  int pcq0 = (0 * 4 + quad) ^ (l16 & 7);
  int pcq1 = (1 * 4 + quad) ^ (l16 & 7);

  for (int t = 0; t < KT; t++) {
    int cur = t & 1, nxt = cur ^ 1;
    int kn = (t + 1) * 64;
    bool st = (t + 1 < KT);

#define G1_PHASE(mh, nh2, STAGES, WAITS)                                      \
    {                                                                         \
      WAITS;                                                                  \
      __builtin_amdgcn_s_barrier();                                           \
      __builtin_amdgcn_sched_barrier(0);                                      \
      bf16x8 af[4][2], bfv[2][2];                                             \
      _Pragma("unroll")                                                       \
      for (int i2 = 0; i2 < 4; i2++) {                                        \
        int row = wm2 * 128 + ((mh) * 4 + i2) * 16 + l16;                     \
        af[i2][0] = *(const bf16x8*)&lds[cur][0][row * 64 + pcq0 * 8];        \
        af[i2][1] = *(const bf16x8*)&lds[cur][0][row * 64 + pcq1 * 8];        \
      }                                                                       \
      _Pragma("unroll")                                                       \
      for (int j2 = 0; j2 < 2; j2++) {                                        \
        int rowb = wn4 * 64 + ((nh2) * 2 + j2) * 16 + l16;                    \
        bfv[j2][0] = *(const bf16x8*)&lds[cur][1][rowb * 64 + pcq0 * 8];      \
        bfv[j2][1] = *(const bf16x8*)&lds[cur][1][rowb * 64 + pcq1 * 8];      \
      }                                                                       \
      if (st) { STAGES; }                                                     \
      asm volatile("s_waitcnt lgkmcnt(0)" ::: "memory");                      \
      __builtin_amdgcn_sched_barrier(0);                                      \
      __builtin_amdgcn_s_setprio(1);                                          \
      _Pragma("unroll")                                                       \
      for (int i2 = 0; i2 < 4; i2++)                                          \
        _Pragma("unroll")                                                     \
        for (int j2 = 0; j2 < 2; j2++)                                        \
          _Pragma("unroll")                                                   \
          for (int kk = 0; kk < 2; kk++)                                      \
            acc[(mh) * 4 + i2][(nh2) * 2 + j2] =                              \
                __builtin_amdgcn_mfma_f32_16x16x32_bf16(                      \
                    af[i2][kk], bfv[j2][kk],                                  \
                    acc[(mh) * 4 + i2][(nh2) * 2 + j2], 0, 0, 0);             \
      __builtin_amdgcn_s_setprio(0);                                          \
    }

    G1_PHASE(0, 0, G1_STAGE(nxt,1,0,kn); G1_STAGE(nxt,1,1,kn),
             if (st) asm volatile("s_waitcnt vmcnt(2)" ::: "memory");
             else    asm volatile("s_waitcnt vmcnt(0)" ::: "memory"));
    G1_PHASE(1, 0, G1_STAGE(nxt,1,2,kn); G1_STAGE(nxt,1,3,kn),
             if (st) asm volatile("s_waitcnt vmcnt(2)" ::: "memory");
             else    asm volatile("s_waitcnt vmcnt(0)" ::: "memory"));
    G1_PHASE(0, 1, G1_STAGE(nxt,0,0,kn); G1_STAGE(nxt,0,2,kn),
             asm volatile("s_waitcnt vmcnt(4)" ::: "memory"));
    G1_PHASE(1, 1, G1_STAGE(nxt,0,1,kn); G1_STAGE(nxt,0,3,kn),
             asm volatile("s_waitcnt vmcnt(6)" ::: "memory"));
#undef G1_PHASE
  }
#undef G1_STAGE

  // epilogue: C/D layout col=lane&15, row=quad*4+reg  [m89-verified]
  bool isv = (n0 >= 3072);
#pragma unroll
  for (int j = 0; j < 4; j++) {
    int n = n0 + wn4 * 64 + j * 16 + l16;
    float bias = (n < 1536) ? bias0[n] : (n < 3072) ? bias1[n - 1536] : bias2[n - 3072];
    if (!isv) {
#pragma unroll
      for (int i = 0; i < 8; i++) {
#pragma unroll
        for (int r = 0; r < 4; r++) {
          int m = m0 + wm2 * 128 + i * 16 + quad * 4 + r;
          C[(size_t)m * N + n] = (__bf16)(acc[i][j][r] + bias);
        }
      }
    } else {
      // fused V transpose: vt[(h*HD+d)*SPAD + m], zero-pad m in [S_LEN, SPAD)
      int nd = n - 3072;
      bf16_t* vrow = vt + ((size_t)(nd >> 7) * HD + (nd & 127)) * SPAD;
#pragma unroll
      for (int i = 0; i < 8; i++) {
        int m = m0 + wm2 * 128 + i * 16 + quad * 4;
        if (m < SPAD) {
          bf16x4 vv;
#pragma unroll
          for (int r = 0; r < 4; r++) {
            float val = acc[i][j][r] + bias;
            vv[r] = (m + r < S_LEN) ? (__bf16)val : (__bf16)0.f;
          }
          *(bf16x4*)&vrow[m] = vv;
        }
      }
    }
  }
}

// ---------------- GEMM2 (128-tile, known-good): C = A @ B^T + bias ----------------

template<bool OUT_BF16>
__global__ __launch_bounds__(256) void gemm_bt_kernel(
    const bf16_t* __restrict__ A, const bf16_t* __restrict__ B, void* __restrict__ C,
    const float* __restrict__ bias0, const float* __restrict__ bias1,
    const float* __restrict__ bias2, int M, int N, int K, int Mvalid) {
  __shared__ bf16_t As[2][128 * 32];
  __shared__ bf16_t Bs[2][128 * 32];
  int tid = threadIdx.x;
  int lane = tid & 63, wave = tid >> 6, quad = lane >> 4, l16 = lane & 15;
  int m0 = blockIdx.y * 128, n0 = blockIdx.x * 128;
  int wm = (wave >> 1) * 64, wn = (wave & 1) * 64;
  const bf16_t* Ab = A + (size_t)m0 * K;
  const bf16_t* Bb = B + (size_t)n0 * K;
  f32x4 acc[4][4] = {};

  int eo0 = tid * 8;
  int row0 = eo0 >> 5, col0 = eo0 & 31;
  int eo1 = (256 + tid) * 8;
  int row1 = eo1 >> 5, col1 = eo1 & 31;

  GLOAD_LDS16(Ab + (size_t)row0 * K + col0, &As[0][eo0]);
  GLOAD_LDS16(Bb + (size_t)row0 * K + col0, &Bs[0][eo0]);
  GLOAD_LDS16(Ab + (size_t)row1 * K + col1, &As[0][eo1]);
  GLOAD_LDS16(Bb + (size_t)row1 * K + col1, &Bs[0][eo1]);
  asm volatile("s_waitcnt vmcnt(0)" ::: "memory");
  __builtin_amdgcn_s_barrier();
  __builtin_amdgcn_sched_barrier(0);

  int KT = K >> 5;
  for (int t = 0; t < KT; t++) {
    int cur = t & 1;
    if (t + 1 < KT) {
      int kn = (t + 1) << 5;
      GLOAD_LDS16(Ab + (size_t)row0 * K + kn + col0, &As[cur ^ 1][eo0]);
      GLOAD_LDS16(Bb + (size_t)row0 * K + kn + col0, &Bs[cur ^ 1][eo0]);
      GLOAD_LDS16(Ab + (size_t)row1 * K + kn + col1, &As[cur ^ 1][eo1]);
      GLOAD_LDS16(Bb + (size_t)row1 * K + kn + col1, &Bs[cur ^ 1][eo1]);
    }
    bf16x8 af[4], bfr[4];
#pragma unroll
    for (int i = 0; i < 4; i++)
      af[i] = *(const bf16x8*)&As[cur][(wm + i * 16 + l16) * 32 + quad * 8];
#pragma unroll
    for (int j = 0; j < 4; j++)
      bfr[j] = *(const bf16x8*)&Bs[cur][(wn + j * 16 + l16) * 32 + quad * 8];
#pragma unroll
    for (int i = 0; i < 4; i++)
#pragma unroll
      for (int j = 0; j < 4; j++)
        acc[i][j] = __builtin_amdgcn_mfma_f32_16x16x32_bf16(af[i], bfr[j], acc[i][j], 0, 0, 0);
    asm volatile("s_waitcnt vmcnt(0) lgkmcnt(0)" ::: "memory");
    __builtin_amdgcn_s_barrier();
    __builtin_amdgcn_sched_barrier(0);
  }
#pragma unroll
  for (int j = 0; j < 4; j++) {
    int n = n0 + wn + j * 16 + l16;
    float bias = (n < 1536) ? bias0[n] : (n < 3072) ? bias1[n - 1536] : bias2[n - 3072];
#pragma unroll
    for (int i = 0; i < 4; i++) {
#pragma unroll
      for (int r = 0; r < 4; r++) {
        int m = m0 + wm + i * 16 + quad * 4 + r;
        float v = acc[i][j][r] + bias;
        if (OUT_BF16) {
          ((bf16_t*)C)[(size_t)m * N + n] = (__bf16)v;
        } else {
          if (m < Mvalid) ((float*)C)[(size_t)m * N + n] = v;
        }
      }
    }
  }
}

// ---------------- RMSNorm + RoPE for q,k ----------------
// q pre-scaled by (1/sqrt(HD)) * log2(e) so flash uses raw v_exp_f32 (2^x).

__global__ __launch_bounds__(256) void rope_qk_kernel(
    const bf16_t* __restrict__ qkv, const float* __restrict__ nqw,
    const float* __restrict__ nkw, const float* __restrict__ fcos,
    const float* __restrict__ fsin, bf16_t* __restrict__ qout,
    bf16_t* __restrict__ kout) {
  int s = blockIdx.x;              // 0..MPAD-1
  int tid = threadIdx.x;
  bool valid = s < S_LEN;
  int f = s / 900, hh = (s / 30) % 30, ww = s % 30;
  __shared__ float red[4];
  for (int which = 0; which < 2; which++) {
    const bf16_t* src = qkv + (size_t)s * NQKV + which * DIM;
    const float* nw = which ? nkw : nqw;
    bf16_t* dst = (which ? kout : qout) + (size_t)s * DIM;
    // 0.12751742686 = (1/sqrt(128)) * log2(e)
    float osc = which ? 1.0f : 0.12751742686f;
    float v[6]; float ss = 0.f;
#pragma unroll
    for (int i = 0; i < 6; i++) {
      v[i] = valid ? (float)src[tid * 6 + i] : 0.f;
      ss += v[i] * v[i];
    }
#pragma unroll
    for (int off = 32; off >= 1; off >>= 1) ss += __shfl_down(ss, off);
    if ((tid & 63) == 0) red[tid >> 6] = ss;
    __syncthreads();
    float tot = red[0] + red[1] + red[2] + red[3];
    float rn = rsqrtf(tot * (1.f / DIM) + EPS_NORM);
    __syncthreads();   // protect red[] before next `which` iteration
#pragma unroll
    for (int i = 0; i < 3; i++) {
      int e0 = tid * 6 + 2 * i;
      int p = e0 >> 1;
      int cc = p & 63;
      int pos = (cc < 22) ? f : (cc < 43) ? hh : ww;  // split [22,21,21]
      float c = fcos[pos * 64 + cc], sn = fsin[pos * 64 + cc];
      float xr = v[2 * i] * rn * nw[e0];
      float xi = v[2 * i + 1] * rn * nw[e0 + 1];
      dst[e0]     = (__bf16)((xr * c - xi * sn) * osc);
      dst[e0 + 1] = (__bf16)((xr * sn + xi * c) * osc);
    }
  }
}

// ---------------- flash attention (R3-exact: best measured 334.6 us) ----------------
// S^T = K Q^T with 32x32x16 MFMA; 2-phase dbuf K/V staging; in-register P
// (T12 cvt_pk + permlane32_swap builtin); log2-domain softmax with defer-max.
// C/D 32x32 layout: col=lane&31, row=(reg&3)+8*(reg>>2)+4*(lane>>5)  [m74/m101]

__global__ __launch_bounds__(256, 2) void flash_attn_kernel(
    const bf16_t* __restrict__ q, const bf16_t* __restrict__ k,
    const bf16_t* __restrict__ vt, bf16_t* __restrict__ o) {
  __shared__ bf16_t Ks[2][64 * 128];
  __shared__ bf16_t Vs[2][64 * 128];
  int head = blockIdx.y;
  int s0 = blockIdx.x * 128;
  int tid = threadIdx.x, w = tid >> 6, lane = tid & 63;
  int l31 = lane & 31, hh = lane >> 5;

  bf16x8 bq[8];
  {
    const bf16_t* qp = &q[(size_t)(s0 + w * 32 + l31) * DIM + head * HD + hh * 8];
#pragma unroll
    for (int kc = 0; kc < 8; kc++) bq[kc] = *(const bf16x8*)(qp + kc * 16);
  }

  float m_i = -1e30f, l_i = 0.f;
  f32x16 oacc[4] = {};

  const int NT = SPAD / 64;   // 85

#pragma unroll
  for (int it = 0; it < 4; it++) {
    int slot = it * 256 + tid;
    int row = slot >> 4, pc = slot & 15;
    int c = pc ^ (row & 15);
    GLOAD_LDS16(k + (size_t)row * DIM + head * HD + c * 8, &Ks[0][slot * 8]);
  }
#pragma unroll
  for (int it = 0; it < 4; it++) {
    int slot = it * 256 + tid;
    int row = slot >> 4, pc = slot & 15;
    int cp = pc ^ (row & 15);
    int d = 2 * row + (cp >> 3);
    GLOAD_LDS16(vt + ((size_t)head * HD + d) * SPAD + (cp & 7) * 8, &Vs[0][slot * 8]);
  }
  asm volatile("s_waitcnt vmcnt(0)" ::: "memory");
  __builtin_amdgcn_s_barrier();
  __builtin_amdgcn_sched_barrier(0);

  for (int t = 0; t < NT; t++) {
    int kt = t * 64;
    int cur = t & 1;

    if (t + 1 < NT) {
      int kn = kt + 64;
#pragma unroll
      for (int it = 0; it < 4; it++) {
        int slot = it * 256 + tid;
        int row = slot >> 4, pc = slot & 15;
        int c = pc ^ (row & 15);
        GLOAD_LDS16(k + (size_t)(kn + row) * DIM + head * HD + c * 8, &Ks[cur ^ 1][slot * 8]);
      }
#pragma unroll
      for (int it = 0; it < 4; it++) {
        int slot = it * 256 + tid;
        int row = slot >> 4, pc = slot & 15;
        int cp = pc ^ (row & 15);
        int d = 2 * row + (cp >> 3);
        GLOAD_LDS16(vt + ((size_t)head * HD + d) * SPAD + kn + (cp & 7) * 8, &Vs[cur ^ 1][slot * 8]);
      }
    }

    f32x16 sacc[2] = {};
    __builtin_amdgcn_s_setprio(1);
#pragma unroll
    for (int ns = 0; ns < 2; ns++) {
      int row = ns * 32 + l31;
#pragma unroll
      for (int kc = 0; kc < 8; kc++) {
        int pc = (kc * 2 + hh) ^ (row & 15);
        bf16x8 ak = *(const bf16x8*)&Ks[cur][row * 128 + pc * 8];
        sacc[ns] = __builtin_amdgcn_mfma_f32_32x32x16_bf16(ak, bq[kc], sacc[ns], 0, 0, 0);
      }
    }
    __builtin_amdgcn_s_setprio(0);

    if (kt + 64 > S_LEN) {
#pragma unroll
      for (int ns = 0; ns < 2; ns++)
#pragma unroll
        for (int r = 0; r < 16; r++) {
          int kvg = kt + ns * 32 + (r & 3) + 8 * (r >> 2) + 4 * hh;
          if (kvg >= S_LEN) sacc[ns][r] = -1e30f;
        }
    }

    float mx;
    {
      float tm[8];
#pragma unroll
      for (int i = 0; i < 8; i++)
        tm[i] = fmaxf(fmaxf(sacc[0][i], sacc[0][i + 8]),
                      fmaxf(sacc[1][i], sacc[1][i + 8]));
#pragma unroll
      for (int i = 0; i < 4; i++) tm[i] = fmaxf(tm[i], tm[i + 4]);
      mx = fmaxf(fmaxf(tm[0], tm[2]), fmaxf(tm[1], tm[3]));
    }
    mx = xhalf_max(mx);
    if (!__all(mx - m_i <= 11.5f)) {   // 11.5 ~= 8*log2(e)
      float mn = fmaxf(m_i, mx);
      float al = __builtin_amdgcn_exp2f(m_i - mn);
      l_i *= al;
#pragma unroll
      for (int dt = 0; dt < 4; dt++)
#pragma unroll
        for (int r = 0; r < 16; r++) oacc[dt][r] *= al;
      m_i = mn;
    }
#pragma unroll
    for (int ns = 0; ns < 2; ns++)
#pragma unroll
      for (int r = 0; r < 16; r++)
        sacc[ns][r] = __builtin_amdgcn_exp2f(sacc[ns][r] - m_i);
    float rs;
    {
      float ts[8];
#pragma unroll
      for (int i = 0; i < 8; i++)
        ts[i] = (sacc[0][i] + sacc[0][i + 8]) + (sacc[1][i] + sacc[1][i + 8]);
#pragma unroll
      for (int i = 0; i < 4; i++) ts[i] += ts[i + 4];
      rs = (ts[0] + ts[2]) + (ts[1] + ts[3]);
    }
    l_i += xhalf_sum(rs);

    __builtin_amdgcn_s_setprio(1);
#pragma unroll
    for (int kvc = 0; kvc < 4; kvc++) {
      int ns = kvc >> 1, rb = (kvc & 1) * 8;
      int w0 = (int)pkbf(sacc[ns][rb + 0], sacc[ns][rb + 1]);
      int w1 = (int)pkbf(sacc[ns][rb + 2], sacc[ns][rb + 3]);
      int w2 = (int)pkbf(sacc[ns][rb + 4], sacc[ns][rb + 5]);
      int w3 = (int)pkbf(sacc[ns][rb + 6], sacc[ns][rb + 7]);
      i32x2 r02 = __builtin_amdgcn_permlane32_swap(w0, w2, false, false);
      i32x2 r13 = __builtin_amdgcn_permlane32_swap(w1, w3, false, false);
      union { unsigned int u[4]; bf16x8 v8; } bpu;
      bpu.u[0] = (unsigned int)r02.x; bpu.u[1] = (unsigned int)r13.x;
      bpu.u[2] = (unsigned int)r02.y; bpu.u[3] = (unsigned int)r13.y;
      bf16x8 bp = bpu.v8;
#pragma unroll
      for (int dt = 0; dt < 4; dt++) {
        int d = dt * 32 + l31;
        int r = d >> 1;
        int cp = ((d & 1) << 3) | (kvc * 2 + hh);
        int pc = cp ^ (r & 15);
        bf16x8 av = *(const bf16x8*)&Vs[cur][r * 128 + pc * 8];
        oacc[dt] = __builtin_amdgcn_mfma_f32_32x32x16_bf16(av, bp, oacc[dt], 0, 0, 0);
      }
    }
    __builtin_amdgcn_s_setprio(0);

    asm volatile("s_waitcnt vmcnt(0) lgkmcnt(0)" ::: "memory");
    __builtin_amdgcn_s_barrier();
    __builtin_amdgcn_sched_barrier(0);
  }

  bf16_t* scr = ((bf16_t*)Ks) + w * (32 * 64);
  float inv = 1.f / l_i;
  int qr = lane >> 1, seg = lane & 1;
  int srow = s0 + w * 32 + qr;
#pragma unroll
  for (int half = 0; half < 2; half++) {
#pragma unroll
    for (int dl = 0; dl < 2; dl++) {
      int dt = half * 2 + dl;
#pragma unroll
      for (int tt = 0; tt < 4; tt++) {
        bf16x4 v;
#pragma unroll
        for (int r4 = 0; r4 < 4; r4++) v[r4] = (__bf16)(oacc[dt][tt * 4 + r4] * inv);
        int c8 = dl * 8 + 2 * tt + hh;
        int pc8 = c8 ^ (l31 & 15);
        *(bf16x4*)&scr[l31 * 64 + pc8 * 4] = v;
      }
    }
#pragma unroll
    for (int i = 0; i < 4; i++) {
      int c8 = seg * 8 + 2 * i;
      bf16x4 lo = *(const bf16x4*)&scr[qr * 64 + ((c8) ^ (qr & 15)) * 4];
      bf16x4 hi = *(const bf16x4*)&scr[qr * 64 + ((c8 + 1) ^ (qr & 15)) * 4];
      bf16x8 val;
#pragma unroll
      for (int j = 0; j < 4; j++) { val[j] = lo[j]; val[j + 4] = hi[j]; }
      if (srow < S_LEN)
        *(bf16x8*)&o[(size_t)srow * DIM + head * HD + half * 64 + seg * 32 + i * 8] = val;
    }
  }
}

// ---------------- launch ----------------

extern "C" void kernel_launch(void* const* d_in, const int* in_sizes, int n_in,
                              void* d_out, int out_size, void* d_ws, size_t ws_size,
                              hipStream_t stream) {
  const float* x    = (const float*)d_in[0];
  const float* q_w  = (const float*)d_in[1];
  const float* q_b  = (const float*)d_in[2];
  const float* k_w  = (const float*)d_in[3];
  const float* k_b  = (const float*)d_in[4];
  const float* v_w  = (const float*)d_in[5];
  const float* v_b  = (const float*)d_in[6];
  const float* o_w  = (const float*)d_in[7];
  const float* o_b  = (const float*)d_in[8];
  const float* nqw  = (const float*)d_in[9];
  const float* nkw  = (const float*)d_in[10];
  const float* fcos = (const float*)d_in[11];
  const float* fsin = (const float*)d_in[12];

  char* ws = (char*)d_ws;
  bf16_t* xb   = (bf16_t*)(ws + 0);           // 5632*1536*2 = 17,301,504
  bf16_t* wqkv = (bf16_t*)(ws + 17301504);    // 14,155,776
  bf16_t* wob  = (bf16_t*)(ws + 31457280);    //  4,718,592
  bf16_t* qkv  = (bf16_t*)(ws + 36175872);    // 5632*4608*2 = 51,904,512
  bf16_t* qb   = (bf16_t*)(ws + 88080384);    // 16,908,288
  bf16_t* kb   = (bf16_t*)(ws + 104988672);   // 16,908,288
  bf16_t* vtb  = (bf16_t*)(ws + 121896960);   // 12*128*5440*2 = 16,711,680 (own region:
                                              //   GEMM1 reads xb while writing vt)
  bf16_t* aob  = (bf16_t*)(ws + 36175872);    // alias qkv (q,k parts dead after rope)

  cvt_all_kernel<<<CVT_NX + CVT_NW + CVT_NO, 256, 0, stream>>>(
      x, q_w, k_w, v_w, o_w, xb, wqkv, wob);

  gemm1_256_kernel<<<dim3(NQKV / 256, MPAD2 / 256), 512, 0, stream>>>(
      xb, wqkv, qkv, vtb, q_b, k_b, v_b);

  rope_qk_kernel<<<MPAD, 256, 0, stream>>>(qkv, nqw, nkw, fcos, fsin, qb, kb);

  flash_attn_kernel<<<dim3(MPAD / 128, NH), 256, 0, stream>>>(qb, kb, vtb, aob);

  gemm_bt_kernel<false><<<dim3(DIM / 128, MPAD / 128), 256, 0, stream>>>(
      aob, wob, d_out, o_b, o_b, o_b, MPAD, DIM, DIM, S_LEN);
}